// Round 14
// baseline (10344.833 us; speedup 1.0000x reference)
//
#include <hip/hip_runtime.h>
#include <stdint.h>
#include <stddef.h>

#define DEV __device__ __forceinline__

typedef float f32x4 __attribute__((ext_vector_type(4)));

// ---------------- threefry2x32 (exact JAX) ----------------
__host__ __device__ inline void tf2x32(uint32_t k0, uint32_t k1,
                                       uint32_t x0, uint32_t x1,
                                       uint32_t* o0, uint32_t* o1) {
  uint32_t ks2 = k0 ^ k1 ^ 0x1BD11BDAu;
  uint32_t ks[3] = {k0, k1, ks2};
  x0 += k0; x1 += k1;
  const uint32_t R[8] = {13u,15u,26u,6u,17u,29u,16u,24u};
  for (int r = 0; r < 5; ++r) {
    const uint32_t* rot = (r & 1) ? (R + 4) : R;
    for (int i = 0; i < 4; ++i) {
      x0 += x1;
      uint32_t d = rot[i];
      x1 = (x1 << d) | (x1 >> (32u - d));
      x1 ^= x0;
    }
    x0 += ks[(r + 1) % 3];
    x1 += ks[(r + 2) % 3] + (uint32_t)(r + 1);
  }
  *o0 = x0; *o1 = x1;
}

DEV float erfinv_approx(float x) {
  float w = -logf((1.0f - x) * (1.0f + x));
  float p;
  if (w < 5.0f) {
    w = w - 2.5f;
    p = 2.81022636e-08f;
    p = fmaf(p, w, 3.43273939e-07f);
    p = fmaf(p, w, -3.5233877e-06f);
    p = fmaf(p, w, -4.39150654e-06f);
    p = fmaf(p, w, 0.00021858087f);
    p = fmaf(p, w, -0.00125372503f);
    p = fmaf(p, w, -0.00417768164f);
    p = fmaf(p, w, 0.246640727f);
    p = fmaf(p, w, 1.50140941f);
  } else {
    w = sqrtf(w) - 3.0f;
    p = -0.000200214257f;
    p = fmaf(p, w, 0.000100950558f);
    p = fmaf(p, w, 0.00134934322f);
    p = fmaf(p, w, -0.00367342844f);
    p = fmaf(p, w, 0.00573950773f);
    p = fmaf(p, w, -0.0076224613f);
    p = fmaf(p, w, 0.00943887047f);
    p = fmaf(p, w, 1.00167406f);
    p = fmaf(p, w, 2.83297682f);
  }
  return p * x;
}

DEV float normal_part(uint32_t ka, uint32_t kb, uint32_t idx) {
  uint32_t b1, b2;
  tf2x32(ka, kb, 0u, idx, &b1, &b2);
  uint32_t bits = b1 ^ b2;
  float f = __uint_as_float((bits >> 9) | 0x3f800000u) - 1.0f;
  const float lo = -0.99999994f;
  float u = f * 2.0f + lo;
  u = fmaxf(lo, u);
  return 1.41421356f * erfinv_approx(u);
}

DEV float lrelu(float x) { return x >= 0.f ? x : 0.2f * x; }
DEV float sigm(float x) { return 1.0f / (1.0f + expf(-x)); }

DEV float gru_out(float ir, float iz, float ig, float hr, float hz, float hg, float hprev) {
  float r = sigm(ir + hr);
  float z = sigm(iz + hz);
  float n = tanhf(ig + r * hg);
  return (1.0f - z) * n + z * hprev;
}

DEV float dot4f(float4 a, float4 b, float acc) {
  return fmaf(a.x, b.x, fmaf(a.y, b.y, fmaf(a.z, b.z, fmaf(a.w, b.w, acc))));
}

template <int K4>
DEV void dot2(const float* __restrict__ h, const float* __restrict__ w0,
              const float* __restrict__ w1, float& a0, float& a1) {
  const float4* h4 = (const float4*)h;
  const float4* p0 = (const float4*)w0;
  const float4* p1 = (const float4*)w1;
  #pragma unroll 4
  for (int k = 0; k < K4; ++k) {
    float4 hv = h4[k];
    float4 v0 = p0[k], v1 = p1[k];
    a0 = dot4f(hv, v0, a0);
    a1 = dot4f(hv, v1, a1);
  }
}

// simple global k-packed 3-gate dot (small K=64 rT dot)
template <int K4>
DEV void dotT3p(const float* __restrict__ hp, int b,
                const float* __restrict__ w0, const float* __restrict__ w1,
                const float* __restrict__ w2, float& a0, float& a1, float& a2) {
  const float4* __restrict__ w04 = (const float4*)w0;
  const float4* __restrict__ w14 = (const float4*)w1;
  const float4* __restrict__ w24 = (const float4*)w2;
  const float4* __restrict__ h4 = (const float4*)hp;
  #pragma unroll
  for (int k4 = 0; k4 < K4; ++k4) {
    float4 hv = h4[k4 * 64 + b];
    a0 = dot4f(w04[k4], hv, a0);
    a1 = dot4f(w14[k4], hv, a1);
    a2 = dot4f(w24[k4], hv, a2);
  }
}

// LDS k-packed 3-gate dot: h tile staged in LDS [k4][b][4].
template <int K4>
DEV void dotT3_lds(const float* __restrict__ hl, int b,
                   const float* __restrict__ w0, const float* __restrict__ w1,
                   const float* __restrict__ w2, float& a0, float& a1, float& a2) {
  const float4* __restrict__ h4 = (const float4*)hl;
  const float4* __restrict__ w04 = (const float4*)w0;
  const float4* __restrict__ w14 = (const float4*)w1;
  const float4* __restrict__ w24 = (const float4*)w2;
  #pragma unroll 8
  for (int k4 = 0; k4 < K4; ++k4) {
    float4 hv = h4[k4 * 64 + b];
    a0 = dot4f(w04[k4], hv, a0);
    a1 = dot4f(w14[k4], hv, a1);
    a2 = dot4f(w24[k4], hv, a2);
  }
}

// cooperative stage for 1024-thread blocks: 8 float4/thread (128 KB tile).
DEV void stage_lds1k(float* __restrict__ dst, const float* __restrict__ src) {
  const float4* __restrict__ s4 = (const float4*)src;
  float4* __restrict__ d4 = (float4*)dst;
  int tid = threadIdx.x;
  float4 v[8];
  #pragma unroll
  for (int u = 0; u < 8; ++u) v[u] = s4[(size_t)u * 1024 + tid];
  #pragma unroll
  for (int u = 0; u < 8; ++u) d4[(size_t)u * 1024 + tid] = v[u];
}

// packed element offset for h[k][b] in k-packed layout
DEV size_t pk(int k, int b) { return (size_t)(k >> 2) * 256 + b * 4 + (k & 3); }

// ---------------- write-through (cross-XCD coherent) access, no cache flushes ----
DEV void coh_store_i(int* p, int v) {
  asm volatile("global_store_dword %0, %1, off sc0 sc1" :: "v"(p), "v"(v) : "memory");
}
DEV void coh_store_f(float* p, float v) {
  asm volatile("global_store_dword %0, %1, off sc0 sc1" :: "v"(p), "v"(v) : "memory");
}
DEV void coh_store_f4(float* p, f32x4 v) {
  asm volatile("global_store_dwordx4 %0, %1, off sc0 sc1" :: "v"(p), "v"(v) : "memory");
}
DEV int coh_load_i(const int* p) {
  int v;
  asm volatile("global_load_dword %0, %1, off sc0 sc1\n\ts_waitcnt vmcnt(0)"
               : "=v"(v) : "v"(p) : "memory");
  return v;
}

// group flag barrier
DEV void flag_barrier(int* __restrict__ flags, int nblk, int myidx, int gen) {
  asm volatile("s_waitcnt vmcnt(0)" ::: "memory");
  __syncthreads();
  if (threadIdx.x == 0) coh_store_i(flags + myidx, gen);
  if ((int)threadIdx.x < nblk) {
    int spins = 0;
    while (coh_load_i(flags + threadIdx.x) < gen) {
      __builtin_amdgcn_s_sleep(16);
      if (++spins > (1 << 19)) break;  // failsafe
    }
  }
  __syncthreads();
}

// one-directional wait: all of another group's flags >= thr.
DEV void wait_group(const int* __restrict__ flags, int nblk, int thr) {
  if ((int)threadIdx.x < nblk) {
    int spins = 0;
    while (coh_load_i(flags + threadIdx.x) < thr) {
      __builtin_amdgcn_s_sleep(16);
      if (++spins > (1 << 19)) break;
    }
  }
  __syncthreads();
}

// 16 waves' results (smem[16][64]) -> coalesced dwordx4 write-through (4KB).
DEV void store_packed_tile16(float* dst_t, const float (*smem)[64], int j0) {
  if (threadIdx.x < 256) {
    int q = threadIdx.x >> 6;       // 4 k-quads
    int bb = threadIdx.x & 63;
    f32x4 v;
    v.x = smem[q * 4 + 0][bb];
    v.y = smem[q * 4 + 1][bb];
    v.z = smem[q * 4 + 2][bb];
    v.w = smem[q * 4 + 3][bb];
    coh_store_f4(dst_t + (size_t)((j0 >> 2) + q) * 256 + bb * 4, v);
  }
}

// ---------------- generic f32 GEMM ----------------
#define GBM 128
#define GBN 128
#define GBK 16

__global__ __launch_bounds__(256) void gemm_nt(
    const float* __restrict__ A, const float* __restrict__ Bt,
    const float* __restrict__ bias, float* __restrict__ C,
    int M, int N, int K, const int* __restrict__ gatherA, int trGI) {
  __shared__ float As[GBK][GBM + 4];
  __shared__ float Bs[GBK][GBN + 4];
  const int bm = blockIdx.y * GBM;
  const int bn = blockIdx.x * GBN;
  const int tid = threadIdx.x;
  const int tx = tid & 15;
  const int ty = tid >> 4;
  float acc[8][8];
  #pragma unroll
  for (int i = 0; i < 8; ++i)
    #pragma unroll
    for (int j = 0; j < 8; ++j) acc[i][j] = 0.f;

  for (int k0 = 0; k0 < K; k0 += GBK) {
    #pragma unroll
    for (int s = 0; s < 2; ++s) {
      int f = tid + s * 256;
      int r = f >> 2, kq = f & 3;
      int row = bm + r;
      float4 v = make_float4(0.f, 0.f, 0.f, 0.f);
      if (row < M) {
        int ar = gatherA ? gatherA[row] : row;
        v = *(const float4*)&A[(size_t)ar * K + k0 + kq * 4];
      }
      As[kq * 4 + 0][r] = v.x;
      As[kq * 4 + 1][r] = v.y;
      As[kq * 4 + 2][r] = v.z;
      As[kq * 4 + 3][r] = v.w;
    }
    #pragma unroll
    for (int s = 0; s < 2; ++s) {
      int f = tid + s * 256;
      int r = f >> 2, kq = f & 3;
      int col = bn + r;
      float4 v = make_float4(0.f, 0.f, 0.f, 0.f);
      if (col < N) v = *(const float4*)&Bt[(size_t)col * K + k0 + kq * 4];
      Bs[kq * 4 + 0][r] = v.x;
      Bs[kq * 4 + 1][r] = v.y;
      Bs[kq * 4 + 2][r] = v.z;
      Bs[kq * 4 + 3][r] = v.w;
    }
    __syncthreads();
    #pragma unroll
    for (int kk = 0; kk < GBK; ++kk) {
      float4 a0 = *(const float4*)&As[kk][ty * 4];
      float4 a1 = *(const float4*)&As[kk][64 + ty * 4];
      float4 b0 = *(const float4*)&Bs[kk][tx * 4];
      float4 b1 = *(const float4*)&Bs[kk][64 + tx * 4];
      float av[8] = {a0.x, a0.y, a0.z, a0.w, a1.x, a1.y, a1.z, a1.w};
      float bv[8] = {b0.x, b0.y, b0.z, b0.w, b1.x, b1.y, b1.z, b1.w};
      #pragma unroll
      for (int i = 0; i < 8; ++i)
        #pragma unroll
        for (int j = 0; j < 8; ++j)
          acc[i][j] = fmaf(av[i], bv[j], acc[i][j]);
    }
    __syncthreads();
  }
  #pragma unroll
  for (int i = 0; i < 8; ++i) {
    int row = bm + ((i < 4) ? (ty * 4 + i) : (64 + ty * 4 + i - 4));
    if (row >= M) continue;
    if (trGI) {
      #pragma unroll
      for (int j = 0; j < 8; ++j) {
        int col = bn + ((j < 4) ? (tx * 4 + j) : (64 + tx * 4 + j - 4));
        if (col >= N) continue;
        float v = acc[i][j] + (bias ? bias[col] : 0.f);
        int bb = row / 48, tt = row - bb * 48;
        C[((size_t)tt * N + col) * 64 + bb] = v;
      }
    } else {
      #pragma unroll
      for (int g = 0; g < 2; ++g) {
        int col0 = bn + g * 64 + tx * 4;
        if (col0 + 3 >= N) continue;
        float4 v;
        v.x = acc[i][g * 4 + 0] + (bias ? bias[col0 + 0] : 0.f);
        v.y = acc[i][g * 4 + 1] + (bias ? bias[col0 + 1] : 0.f);
        v.z = acc[i][g * 4 + 2] + (bias ? bias[col0 + 2] : 0.f);
        v.w = acc[i][g * 4 + 3] + (bias ? bias[col0 + 3] : 0.f);
        *(float4*)&C[(size_t)row * N + col0] = v;
      }
    }
  }
}

// ---------------- misc small kernels ----------------
__global__ void k_transpose(const float* __restrict__ W, float* __restrict__ Wt,
                            int rows, int cols) {
  int idx = blockIdx.x * 256 + threadIdx.x;
  if (idx >= rows * cols) return;
  int r = idx / cols, c = idx % cols;
  Wt[(size_t)c * rows + r] = W[idx];
}

__global__ void k_count_deg(const int* __restrict__ dst, int* __restrict__ deg, int nE) {
  int e = blockIdx.x * 256 + threadIdx.x;
  if (e < nE) atomicAdd(&deg[dst[e]], 1);
}

__global__ __launch_bounds__(1024) void k_scan(const int* __restrict__ deg,
                                               int* __restrict__ off,
                                               int* __restrict__ cursor, int n) {
  __shared__ int tmp[1024];
  __shared__ int carry_s;
  if (threadIdx.x == 0) carry_s = 0;
  __syncthreads();
  for (int base = 0; base < n; base += 1024) {
    int i = base + (int)threadIdx.x;
    int v = (i < n) ? deg[i] : 0;
    tmp[threadIdx.x] = v;
    __syncthreads();
    for (int s = 1; s < 1024; s <<= 1) {
      int t = (threadIdx.x >= (unsigned)s) ? tmp[threadIdx.x - s] : 0;
      __syncthreads();
      tmp[threadIdx.x] += t;
      __syncthreads();
    }
    int incl = tmp[threadIdx.x];
    int base_c = carry_s;
    int excl = incl - v;
    if (i < n) { off[i] = base_c + excl; cursor[i] = base_c + excl; }
    __syncthreads();
    if (threadIdx.x == 1023) carry_s = base_c + incl;
    __syncthreads();
  }
  if (threadIdx.x == 0) off[n] = carry_s;
}

__global__ void k_scatter(const int* __restrict__ dst, int* __restrict__ cursor,
                          int* __restrict__ csr, int nE) {
  int e = blockIdx.x * 256 + threadIdx.x;
  if (e < nE) {
    int pos = atomicAdd(&cursor[dst[e]], 1);
    csr[pos] = e;
  }
}

__global__ void k_alpha(const float* __restrict__ xW, const float* __restrict__ att_src,
                        const float* __restrict__ att_dst, float* __restrict__ as_,
                        float* __restrict__ ad_) {
  int i = blockIdx.x * 256 + threadIdx.x;
  if (i >= 80000) return;
  int n = i >> 2, h = i & 3;
  const float* xr = xW + (size_t)n * 256 + h * 64;
  const float* s = att_src + h * 64;
  const float* d = att_dst + h * 64;
  float a = 0.f, b = 0.f;
  dot2<16>(xr, s, d, a, b);
  as_[i] = a;
  ad_[i] = b;
}

__global__ __launch_bounds__(256) void k_gat_node(
    const float* __restrict__ xW, const float* __restrict__ as_,
    const float* __restrict__ ad_, const int* __restrict__ off,
    const int* __restrict__ csr, const int* __restrict__ esrc,
    const float* __restrict__ eattr, const float* __restrict__ gat_bias,
    float* __restrict__ p) {
  int n = blockIdx.x;
  int h = threadIdx.x >> 6;
  int c = threadIdx.x & 63;
  int s0 = off[n], s1 = off[n + 1];
  float adn = ad_[n * 4 + h];
  float m = -3.0e38f;
  for (int idx = s0; idx < s1; ++idx) {
    int e = csr[idx];
    int s = esrc[e];
    float ev = lrelu(as_[s * 4 + h] + adn);
    m = fmaxf(m, ev);
  }
  float sum = 0.f;
  for (int idx = s0; idx < s1; ++idx) {
    int e = csr[idx];
    int s = esrc[e];
    float ev = lrelu(as_[s * 4 + h] + adn);
    sum += expf(ev - m);
  }
  float acc = 0.f;
  for (int idx = s0; idx < s1; ++idx) {
    int e = csr[idx];
    int s = esrc[e];
    float ev = lrelu(as_[s * 4 + h] + adn);
    float w = expf(ev - m) / (sum + 1e-16f) * eattr[e];
    acc = fmaf(w, xW[(size_t)s * 256 + h * 64 + c], acc);
  }
  p[(size_t)n * 256 + h * 64 + c] = acc + gat_bias[h * 64 + c];
}

__global__ void k_build_X(const float* __restrict__ p, const float* __restrict__ tt,
                          const float* __restrict__ ct, const int* __restrict__ bx,
                          const int* __restrict__ btm, const int* __restrict__ bct,
                          float* __restrict__ X) {
  int idx = blockIdx.x * 256 + threadIdx.x;
  if (idx >= 3072 * 768) return;
  int rl = idx / 768, c = idx % 768;
  float v;
  if (c < 256) v = p[(size_t)bx[rl] * 256 + c];
  else if (c < 512) v = tt[(size_t)btm[rl] * 256 + (c - 256)];
  else v = ct[(size_t)bct[rl] * 256 + (c - 512)];
  X[idx] = v;
}

// ---------------- persistent fused GRU scans (1024-thread blocks) ----------------
// 16 waves/block = 16 j per block; 4x fewer blocks stage the 128KB h tile.

// P1: bidirectional GRU. 64 blocks; blocks 0-31 fwd, 32-63 bwd (independent).
__global__ __launch_bounds__(1024, 1) void k_gru_bidir_fused(
    const float* __restrict__ giT_f, const float* __restrict__ giT_b,
    const float* __restrict__ Wh_f, const float* __restrict__ bh_f,
    const float* __restrict__ Wh_b, const float* __restrict__ bh_b,
    float* __restrict__ features, float* __restrict__ hTb,
    int* __restrict__ flags) {
  __shared__ float lds_h[32768];
  __shared__ float smem[16][64];
  int w = threadIdx.x >> 6;
  int b = threadIdx.x & 63;
  int dir = blockIdx.x >> 5;
  int gbid = blockIdx.x & 31;
  int j0 = gbid * 16;
  int j = j0 + w;
  int* gflags = flags + dir * 128;
  const float* Wh = dir ? Wh_b : Wh_f;
  const float* bh = dir ? bh_b : bh_f;
  const float* gi = dir ? giT_b : giT_f;
  const float* w0 = Wh + (size_t)j * 512;
  const float* w1 = Wh + (size_t)(512 + j) * 512;
  const float* w2 = Wh + (size_t)(1024 + j) * 512;
  float bhr = bh[j], bhz = bh[512 + j], bhg = bh[1024 + j];
  float* hD = hTb + (size_t)dir * 48 * 32768;
  for (int s = 0; s < 48; ++s) {
    int t = dir ? (47 - s) : s;
    const float* gir = gi + (size_t)t * 98304;
    float giv0 = gir[j * 64 + b];
    float giv1 = gir[(512 + j) * 64 + b];
    float giv2 = gir[(1024 + j) * 64 + b];
    float hr = bhr, hz = bhz, hg = bhg, hprev = 0.f;
    if (s > 0) {
      int tp = dir ? (t + 1) : (t - 1);
      stage_lds1k(lds_h, hD + (size_t)tp * 32768);
      __syncthreads();
      dotT3_lds<128>(lds_h, b, w0, w1, w2, hr, hz, hg);
      hprev = lds_h[pk(j, b)];
    }
    float hnew = gru_out(giv0, giv1, giv2, hr, hz, hg, hprev);
    smem[w][b] = hnew;
    features[((size_t)(b * 48 + t)) * 1024 + dir * 512 + j] = hnew;
    __syncthreads();
    store_packed_tile16(hD + (size_t)t * 32768, smem, j0);
    flag_barrier(gflags, 32, gbid, s + 1);
  }
}

// P2: u-GRU over features. 32 blocks x 1024 thr.
__global__ __launch_bounds__(1024, 1) void k_gru_u_fused(
    const float* __restrict__ giT, const float* __restrict__ Wh,
    const float* __restrict__ bh, float* __restrict__ r_feat,
    float* __restrict__ hU, int* __restrict__ flags) {
  __shared__ float lds_h[32768];
  __shared__ float smem[16][64];
  int w = threadIdx.x >> 6;
  int b = threadIdx.x & 63;
  int j0 = blockIdx.x * 16;
  int j = j0 + w;
  const float* w0 = Wh + (size_t)j * 512;
  const float* w1 = Wh + (size_t)(512 + j) * 512;
  const float* w2 = Wh + (size_t)(1024 + j) * 512;
  float bhr = bh[j], bhz = bh[512 + j], bhg = bh[1024 + j];
  for (int s = 0; s < 48; ++s) {
    const float* gir = giT + (size_t)s * 98304;
    float giv0 = gir[j * 64 + b];
    float giv1 = gir[(512 + j) * 64 + b];
    float giv2 = gir[(1024 + j) * 64 + b];
    float hr = bhr, hz = bhz, hg = bhg, hprev = 0.f;
    if (s > 0) {
      stage_lds1k(lds_h, hU + (size_t)(s - 1) * 32768);
      __syncthreads();
      dotT3_lds<128>(lds_h, b, w0, w1, w2, hr, hz, hg);
      hprev = lds_h[pk(j, b)];
    }
    float hnew = gru_out(giv0, giv1, giv2, hr, hz, hg, hprev);
    smem[w][b] = hnew;
    r_feat[((size_t)(b * 48 + s)) * 512 + j] = hnew;
    __syncthreads();
    store_packed_tile16(hU + (size_t)s * 32768, smem, j0);
    flag_barrier(flags, 32, blockIdx.x, s + 1);
  }
}

// P3: prior double-GRU, producer/consumer. 64 blocks: 0-31 cell1, 32-63 cell2.
__global__ __launch_bounds__(1024, 1) void k_prior_fused(
    const float* __restrict__ r_post,
    const float* __restrict__ Wp1_i, const float* __restrict__ Wp1_h,
    const float* __restrict__ bp1_i, const float* __restrict__ bp1_h,
    const float* __restrict__ Wp2_i, const float* __restrict__ Wp2_h,
    const float* __restrict__ bp2_i, const float* __restrict__ bp2_h,
    float* __restrict__ h1S, float* __restrict__ h2S,
    float* __restrict__ rT, int* __restrict__ flags) {
  __shared__ float lds_h[32768];
  __shared__ float smem[16][64];
  int w = threadIdx.x >> 6;
  int b = threadIdx.x & 63;
  int cell = blockIdx.x >> 5;
  int gbid = blockIdx.x & 31;
  int j0 = gbid * 16;
  int j = j0 + w;
  int* flagsA = flags;
  int* flagsB = flags + 128;

  if (cell == 0) {
    int tid = gbid * 1024 + threadIdx.x;
    for (int x = tid; x < 48 * 64 * 64; x += 32768) {
      int b0 = x & 63;
      int i0 = (x >> 6) & 63;
      int t0 = x >> 12;
      coh_store_f(rT + (size_t)t0 * 4096 + pk(i0, b0),
                  r_post[((size_t)(b0 * 48 + t0)) * 64 + i0]);
    }
    flag_barrier(flagsA, 32, gbid, 1);

    const float* wi0 = Wp1_i + (size_t)j * 64;
    const float* wi1 = Wp1_i + (size_t)(512 + j) * 64;
    const float* wi2 = Wp1_i + (size_t)(1024 + j) * 64;
    const float* wh0 = Wp1_h + (size_t)j * 512;
    const float* wh1 = Wp1_h + (size_t)(512 + j) * 512;
    const float* wh2 = Wp1_h + (size_t)(1024 + j) * 512;
    float bir = bp1_i[j], biz = bp1_i[512 + j], big = bp1_i[1024 + j];
    float bhr = bp1_h[j], bhz = bp1_h[512 + j], bhg = bp1_h[1024 + j];
    for (int k = 0; k < 48; ++k) {
      float ir = bir, iz = biz, ig = big;
      float hr = bhr, hz = bhz, hg = bhg, hprev = 0.f;
      if (k > 0) {
        stage_lds1k(lds_h, h1S + (size_t)(k - 1) * 32768);
        dotT3p<16>(rT + (size_t)(k - 1) * 4096, b, wi0, wi1, wi2, ir, iz, ig);
        __syncthreads();
        dotT3_lds<128>(lds_h, b, wh0, wh1, wh2, hr, hz, hg);
        hprev = lds_h[pk(j, b)];
      }
      smem[w][b] = gru_out(ir, iz, ig, hr, hz, hg, hprev);
      __syncthreads();
      store_packed_tile16(h1S + (size_t)k * 32768, smem, j0);
      flag_barrier(flagsA, 32, gbid, k + 2);
    }
  } else {
    const float* wi0 = Wp2_i + (size_t)j * 512;
    const float* wi1 = Wp2_i + (size_t)(512 + j) * 512;
    const float* wi2 = Wp2_i + (size_t)(1024 + j) * 512;
    const float* wh0 = Wp2_h + (size_t)j * 512;
    const float* wh1 = Wp2_h + (size_t)(512 + j) * 512;
    const float* wh2 = Wp2_h + (size_t)(1024 + j) * 512;
    float bir = bp2_i[j], biz = bp2_i[512 + j], big = bp2_i[1024 + j];
    float bhr = bp2_h[j], bhz = bp2_h[512 + j], bhg = bp2_h[1024 + j];
    for (int t = 0; t < 48; ++t) {
      wait_group(flagsA, 32, t + 2);
      stage_lds1k(lds_h, h1S + (size_t)t * 32768);
      __syncthreads();
      float ir = bir, iz = biz, ig = big;
      dotT3_lds<128>(lds_h, b, wi0, wi1, wi2, ir, iz, ig);
      float hr = bhr, hz = bhz, hg = bhg, hprev = 0.f;
      if (t > 0) {
        __syncthreads();
        stage_lds1k(lds_h, h2S + (size_t)(t - 1) * 32768);
        __syncthreads();
        dotT3_lds<128>(lds_h, b, wh0, wh1, wh2, hr, hz, hg);
        hprev = lds_h[pk(j, b)];
      }
      smem[w][b] = gru_out(ir, iz, ig, hr, hz, hg, hprev);
      __syncthreads();
      store_packed_tile16(h2S + (size_t)t * 32768, smem, j0);
      flag_barrier(flagsB, 32, gbid, t + 1);
    }
  }
}

// ---------------- heads / outputs ----------------
__global__ void k_s_head(const float* __restrict__ features,
                         const float* __restrict__ Ws_m, const float* __restrict__ bs_m,
                         const float* __restrict__ Ws_lv, const float* __restrict__ bs_lv,
                         float* __restrict__ out, uint32_t ka, uint32_t kb) {
  int idx = blockIdx.x * 256 + threadIdx.x;
  if (idx >= 4096) return;
  int i = idx & 63, b = idx >> 6;
  const float* fr = features + ((size_t)(b * 48 + 47)) * 1024;
  const float* bk = features + ((size_t)(b * 48 + 0)) * 1024 + 512;
  const float* wm = Ws_m + (size_t)i * 1024;
  const float* wl = Ws_lv + (size_t)i * 1024;
  float m = 0.f, lv = 0.f;
  dot2<128>(fr, wm, wl, m, lv);
  dot2<128>(bk, wm + 512, wl + 512, m, lv);
  m = lrelu(m + bs_m[i]);
  lv = lrelu(lv + bs_lv[i]);
  float nz = normal_part(ka, kb, (uint32_t)idx);
  out[idx] = m;
  out[4096 + idx] = lv;
  out[8192 + idx] = m + nz * expf(0.5f * lv);
}

__global__ void k_r_head(const float* __restrict__ r_feat,
                         const float* __restrict__ Wr_m, const float* __restrict__ br_m,
                         const float* __restrict__ Wr_lv, const float* __restrict__ br_lv,
                         float* __restrict__ out, uint32_t ka, uint32_t kb) {
  int idx = blockIdx.x * 256 + threadIdx.x;
  if (idx >= 196608) return;
  int i = idx & 63;
  int bt = idx >> 6;
  const float* f = r_feat + (size_t)bt * 512;
  float m = 0.f, lv = 0.f;
  dot2<128>(f, Wr_m + (size_t)i * 512, Wr_lv + (size_t)i * 512, m, lv);
  m += br_m[i];
  lv += br_lv[i];
  float nz = normal_part(ka, kb, (uint32_t)idx);
  out[12288 + idx] = m;
  out[208896 + idx] = lv;
  out[405504 + idx] = m + nz * expf(0.5f * lv);
}

__global__ void k_prior_out(const float* __restrict__ h2S,
                            const float* __restrict__ Wpm, const float* __restrict__ bpm,
                            const float* __restrict__ Wplv, const float* __restrict__ bplv,
                            float* __restrict__ out, uint32_t ka, uint32_t kb) {
  int idx = blockIdx.x * 256 + threadIdx.x;
  if (idx >= 196608) return;
  int i = idx & 63;
  int bt = idx >> 6;
  int b = bt & 63;
  int t = bt >> 6;
  const float4* h4 = (const float4*)(h2S + (size_t)t * 32768);
  const float4* wm4 = (const float4*)(Wpm + (size_t)i * 512);
  const float4* wl4 = (const float4*)(Wplv + (size_t)i * 512);
  float m = 0.f, lv = 0.f;
  #pragma unroll 8
  for (int k4 = 0; k4 < 128; ++k4) {
    float4 hv = h4[k4 * 64 + b];
    m = dot4f(wm4[k4], hv, m);
    lv = dot4f(wl4[k4], hv, lv);
  }
  m += bpm[i];
  lv += bplv[i];
  float ep = normal_part(ka, kb, (uint32_t)idx);
  float rp = m + ep * expf(0.5f * lv);
  size_t o = ((size_t)b * 48 + t) * 64 + i;
  out[602112 + o] = m;
  out[798720 + o] = lv;
  out[995328 + o] = rp;
}

__global__ void k_build_zf(const float* __restrict__ out, float* __restrict__ zf) {
  int idx = blockIdx.x * 256 + threadIdx.x;
  if (idx >= 3072 * 128) return;
  int row = idx >> 7, c = idx & 127;
  float v;
  if (c < 64) v = out[405504 + row * 64 + c];
  else v = out[8192 + (row / 48) * 64 + (c - 64)];
  zf[idx] = v;
}

// ---------------- launcher ----------------
extern "C" void kernel_launch(void* const* d_in, const int* in_sizes, int n_in,
                              void* d_out, int out_size, void* d_ws, size_t ws_size,
                              hipStream_t stream) {
  const int* graph_x = (const int*)d_in[0];
  const int* edge_index = (const int*)d_in[1];
  const float* edge_attr = (const float*)d_in[2];
  const int* batch_x = (const int*)d_in[3];
  const int* batch_time = (const int*)d_in[4];
  const int* batch_cat = (const int*)d_in[5];
  const float* node_emb = (const float*)d_in[8];
  const float* W_gat = (const float*)d_in[9];
  const float* att_src = (const float*)d_in[10];
  const float* att_dst = (const float*)d_in[11];
  const float* gat_bias = (const float*)d_in[12];
  const float* time_table = (const float*)d_in[13];
  const float* cat_table = (const float*)d_in[14];
  const float* W_w = (const float*)d_in[15];
  const float* b_w = (const float*)d_in[16];
  const float* Wi_f = (const float*)d_in[17];
  const float* Wh_f = (const float*)d_in[18];
  const float* bi_f = (const float*)d_in[19];
  const float* bh_f = (const float*)d_in[20];
  const float* Wi_bw = (const float*)d_in[21];
  const float* Wh_bw = (const float*)d_in[22];
  const float* bi_bw = (const float*)d_in[23];
  const float* bh_bw = (const float*)d_in[24];
  const float* Wi_u = (const float*)d_in[25];
  const float* Wh_u = (const float*)d_in[26];
  const float* bi_u = (const float*)d_in[27];
  const float* bh_u = (const float*)d_in[28];
  const float* Ws_m = (const float*)d_in[29];
  const float* bs_m = (const float*)d_in[30];
  const float* Ws_lv = (const float*)d_in[31];
  const float* bs_lv = (const float*)d_in[32];
  const float* Wr_m = (const float*)d_in[33];
  const float* br_m = (const float*)d_in[34];
  const float* Wr_lv = (const float*)d_in[35];
  const float* br_lv = (const float*)d_in[36];
  const float* Wp1_i = (const float*)d_in[37];
  const float* Wp1_h = (const float*)d_in[38];
  const float* bp1_i = (const float*)d_in[39];
  const float* bp1_h = (const float*)d_in[40];
  const float* Wp2_i = (const float*)d_in[41];
  const float* Wp2_h = (const float*)d_in[42];
  const float* bp2_i = (const float*)d_in[43];
  const float* bp2_h = (const float*)d_in[44];
  const float* Wpm = (const float*)d_in[45];
  const float* bpm = (const float*)d_in[46];
  const float* Wplv = (const float*)d_in[47];
  const float* bplv = (const float*)d_in[48];
  const float* Wd = (const float*)d_in[49];
  const float* bd = (const float*)d_in[50];
  float* out = (float*)d_out;

  uint32_t k1a, k1b, k2a, k2b, k3a, k3b;
  tf2x32(0u, 42u, 0u, 0u, &k1a, &k1b);
  tf2x32(0u, 42u, 0u, 1u, &k2a, &k2b);
  tf2x32(0u, 42u, 0u, 2u, &k3a, &k3b);

  float* ws = (float*)d_ws;
  size_t o = 0;
  auto alloc = [&](size_t n) { float* q = ws + o; o += n; return q; };
  float* R1 = alloc(5120000);
  float* R2 = alloc(5120000);
  float* R3 = alloc(4718592);
  float* R4 = alloc(786432);
  float* as_ = alloc(80000);
  float* ad_ = alloc(80000);
  float* Wgt = alloc(65536);
  int* deg = (int*)alloc(20000);
  int* off = (int*)alloc(20001);
  int* cursor = (int*)alloc(20000);
  int* csr = (int*)alloc(320000);
  float* rT = alloc(196608);
  int* flags = (int*)alloc(1024);

  float* xW = R1;
  float* features = R1;
  float* r_feat = R1 + 3145728;
  float* p = R2;
  float* giT_b = R2;
  float* hU = R2;
  float* X = R3;
  float* giT_f = R3;
  float* giT_u = R3;
  float* h1S = R3;
  float* h2S = R3 + 1572864;
  float* ph = R4;
  float* zf = R4;
  float* hTb = out + 1191936;

  const int* esrc = edge_index;
  const int* edst = edge_index + 320000;

  dim3 B(256);

  (void)hipMemsetAsync(deg, 0, 20000 * sizeof(int), stream);
  (void)hipMemsetAsync(flags, 0, 1024 * sizeof(int), stream);

  // ---- GAT ----
  k_transpose<<<dim3(256), B, 0, stream>>>(W_gat, Wgt, 256, 256);
  k_count_deg<<<dim3(1250), B, 0, stream>>>(edst, deg, 320000);
  k_scan<<<dim3(1), dim3(1024), 0, stream>>>(deg, off, cursor, 20000);
  k_scatter<<<dim3(1250), B, 0, stream>>>(edst, cursor, csr, 320000);
  gemm_nt<<<dim3(2, 157), B, 0, stream>>>(node_emb, Wgt, nullptr, xW,
                                          20000, 256, 256, graph_x, 0);
  k_alpha<<<dim3(313), B, 0, stream>>>(xW, att_src, att_dst, as_, ad_);
  k_gat_node<<<dim3(20000), B, 0, stream>>>(xW, as_, ad_, off, csr, esrc,
                                            edge_attr, gat_bias, p);

  // ---- embed concat + W_w ----
  k_build_X<<<dim3(9216), B, 0, stream>>>(p, time_table, cat_table, batch_x,
                                          batch_time, batch_cat, X);
  gemm_nt<<<dim3(2, 24), B, 0, stream>>>(X, W_w, b_w, ph, 3072, 256, 768,
                                         nullptr, 0);

  // ---- gi precompute + fused bidirectional GRU ----
  gemm_nt<<<dim3(12, 24), B, 0, stream>>>(ph, Wi_f, bi_f, giT_f, 3072, 1536, 256,
                                          nullptr, 1);
  gemm_nt<<<dim3(12, 24), B, 0, stream>>>(ph, Wi_bw, bi_bw, giT_b, 3072, 1536, 256,
                                          nullptr, 1);
  k_gru_bidir_fused<<<dim3(64), dim3(1024), 0, stream>>>(
      giT_f, giT_b, Wh_f, bh_f, Wh_bw, bh_bw, features, hTb, flags);

  // ---- s head ----
  k_s_head<<<dim3(16), B, 0, stream>>>(features, Ws_m, bs_m, Ws_lv, bs_lv,
                                       out, k1a, k1b);

  // ---- r_feat GRU (fused) ----
  gemm_nt<<<dim3(12, 24), B, 0, stream>>>(features, Wi_u, bi_u, giT_u,
                                          3072, 1536, 1024, nullptr, 1);
  k_gru_u_fused<<<dim3(32), dim3(1024), 0, stream>>>(giT_u, Wh_u, bh_u, r_feat,
                                                     hU, flags + 256);

  // ---- r head ----
  k_r_head<<<dim3(768), B, 0, stream>>>(r_feat, Wr_m, br_m, Wr_lv, br_lv,
                                        out, k2a, k2b);

  // ---- prior scan (producer/consumer) ----
  k_prior_fused<<<dim3(64), dim3(1024), 0, stream>>>(
      out + 405504, Wp1_i, Wp1_h, bp1_i, bp1_h, Wp2_i, Wp2_h, bp2_i, bp2_h,
      h1S, h2S, rT, flags + 384);
  k_prior_out<<<dim3(768), B, 0, stream>>>(h2S, Wpm, bpm, Wplv, bplv,
                                           out, k3a, k3b);

  // ---- recon ----
  k_build_zf<<<dim3(1536), B, 0, stream>>>(out, zf);
  gemm_nt<<<dim3(157, 24), B, 0, stream>>>(zf, Wd, bd, out + 1191936,
                                           3072, 20000, 128, nullptr, 0);
}

// Round 15
// 4745.845 us; speedup vs baseline: 2.1798x; 2.1798x over previous
//
#include <hip/hip_runtime.h>
#include <stdint.h>
#include <stddef.h>

#define DEV __device__ __forceinline__

typedef float f32x4 __attribute__((ext_vector_type(4)));

// ---------------- threefry2x32 (exact JAX) ----------------
__host__ __device__ inline void tf2x32(uint32_t k0, uint32_t k1,
                                       uint32_t x0, uint32_t x1,
                                       uint32_t* o0, uint32_t* o1) {
  uint32_t ks2 = k0 ^ k1 ^ 0x1BD11BDAu;
  uint32_t ks[3] = {k0, k1, ks2};
  x0 += k0; x1 += k1;
  const uint32_t R[8] = {13u,15u,26u,6u,17u,29u,16u,24u};
  for (int r = 0; r < 5; ++r) {
    const uint32_t* rot = (r & 1) ? (R + 4) : R;
    for (int i = 0; i < 4; ++i) {
      x0 += x1;
      uint32_t d = rot[i];
      x1 = (x1 << d) | (x1 >> (32u - d));
      x1 ^= x0;
    }
    x0 += ks[(r + 1) % 3];
    x1 += ks[(r + 2) % 3] + (uint32_t)(r + 1);
  }
  *o0 = x0; *o1 = x1;
}

DEV float erfinv_approx(float x) {
  float w = -logf((1.0f - x) * (1.0f + x));
  float p;
  if (w < 5.0f) {
    w = w - 2.5f;
    p = 2.81022636e-08f;
    p = fmaf(p, w, 3.43273939e-07f);
    p = fmaf(p, w, -3.5233877e-06f);
    p = fmaf(p, w, -4.39150654e-06f);
    p = fmaf(p, w, 0.00021858087f);
    p = fmaf(p, w, -0.00125372503f);
    p = fmaf(p, w, -0.00417768164f);
    p = fmaf(p, w, 0.246640727f);
    p = fmaf(p, w, 1.50140941f);
  } else {
    w = sqrtf(w) - 3.0f;
    p = -0.000200214257f;
    p = fmaf(p, w, 0.000100950558f);
    p = fmaf(p, w, 0.00134934322f);
    p = fmaf(p, w, -0.00367342844f);
    p = fmaf(p, w, 0.00573950773f);
    p = fmaf(p, w, -0.0076224613f);
    p = fmaf(p, w, 0.00943887047f);
    p = fmaf(p, w, 1.00167406f);
    p = fmaf(p, w, 2.83297682f);
  }
  return p * x;
}

DEV float normal_part(uint32_t ka, uint32_t kb, uint32_t idx) {
  uint32_t b1, b2;
  tf2x32(ka, kb, 0u, idx, &b1, &b2);
  uint32_t bits = b1 ^ b2;
  float f = __uint_as_float((bits >> 9) | 0x3f800000u) - 1.0f;
  const float lo = -0.99999994f;
  float u = f * 2.0f + lo;
  u = fmaxf(lo, u);
  return 1.41421356f * erfinv_approx(u);
}

DEV float lrelu(float x) { return x >= 0.f ? x : 0.2f * x; }
DEV float sigm(float x) { return 1.0f / (1.0f + expf(-x)); }

DEV float gru_out(float ir, float iz, float ig, float hr, float hz, float hg, float hprev) {
  float r = sigm(ir + hr);
  float z = sigm(iz + hz);
  float n = tanhf(ig + r * hg);
  return (1.0f - z) * n + z * hprev;
}

DEV float dot4f(float4 a, float4 b, float acc) {
  return fmaf(a.x, b.x, fmaf(a.y, b.y, fmaf(a.z, b.z, fmaf(a.w, b.w, acc))));
}

template <int K4>
DEV void dot2(const float* __restrict__ h, const float* __restrict__ w0,
              const float* __restrict__ w1, float& a0, float& a1) {
  const float4* h4 = (const float4*)h;
  const float4* p0 = (const float4*)w0;
  const float4* p1 = (const float4*)w1;
  #pragma unroll 4
  for (int k = 0; k < K4; ++k) {
    float4 hv = h4[k];
    float4 v0 = p0[k], v1 = p1[k];
    a0 = dot4f(hv, v0, a0);
    a1 = dot4f(hv, v1, a1);
  }
}

// simple global k-packed 3-gate dot (small K=64 rT dot)
template <int K4>
DEV void dotT3p(const float* __restrict__ hp, int b,
                const float* __restrict__ w0, const float* __restrict__ w1,
                const float* __restrict__ w2, float& a0, float& a1, float& a2) {
  const float4* __restrict__ w04 = (const float4*)w0;
  const float4* __restrict__ w14 = (const float4*)w1;
  const float4* __restrict__ w24 = (const float4*)w2;
  const float4* __restrict__ h4 = (const float4*)hp;
  #pragma unroll
  for (int k4 = 0; k4 < K4; ++k4) {
    float4 hv = h4[k4 * 64 + b];
    a0 = dot4f(w04[k4], hv, a0);
    a1 = dot4f(w14[k4], hv, a1);
    a2 = dot4f(w24[k4], hv, a2);
  }
}

// LDS k-packed 3-gate dot: h tile staged in LDS [k4][b][4].
template <int K4>
DEV void dotT3_lds(const float* __restrict__ hl, int b,
                   const float* __restrict__ w0, const float* __restrict__ w1,
                   const float* __restrict__ w2, float& a0, float& a1, float& a2) {
  const float4* __restrict__ h4 = (const float4*)hl;
  const float4* __restrict__ w04 = (const float4*)w0;
  const float4* __restrict__ w14 = (const float4*)w1;
  const float4* __restrict__ w24 = (const float4*)w2;
  #pragma unroll 8
  for (int k4 = 0; k4 < K4; ++k4) {
    float4 hv = h4[k4 * 64 + b];
    a0 = dot4f(w04[k4], hv, a0);
    a1 = dot4f(w14[k4], hv, a1);
    a2 = dot4f(w24[k4], hv, a2);
  }
}

// cooperative stage: N16 float4 per thread, global -> LDS, 16-deep batches.
template <int N16>
DEV void stage_lds(float* __restrict__ dst, const float* __restrict__ src) {
  const float4* __restrict__ s4 = (const float4*)src;
  float4* __restrict__ d4 = (float4*)dst;
  int tid = threadIdx.x;
  constexpr int CH = (N16 < 16) ? N16 : 16;
  #pragma unroll
  for (int r = 0; r < N16; r += CH) {
    float4 v[CH];
    #pragma unroll
    for (int u = 0; u < CH; ++u) v[u] = s4[(size_t)(r + u) * 256 + tid];
    #pragma unroll
    for (int u = 0; u < CH; ++u) d4[(size_t)(r + u) * 256 + tid] = v[u];
  }
}

// packed element offset for h[k][b] in k-packed layout
DEV size_t pk(int k, int b) { return (size_t)(k >> 2) * 256 + b * 4 + (k & 3); }

// ---------------- write-through (cross-XCD coherent) access, no cache flushes ----
DEV void coh_store_i(int* p, int v) {
  asm volatile("global_store_dword %0, %1, off sc0 sc1" :: "v"(p), "v"(v) : "memory");
}
DEV void coh_store_f(float* p, float v) {
  asm volatile("global_store_dword %0, %1, off sc0 sc1" :: "v"(p), "v"(v) : "memory");
}
DEV void coh_store_f4(float* p, f32x4 v) {
  asm volatile("global_store_dwordx4 %0, %1, off sc0 sc1" :: "v"(p), "v"(v) : "memory");
}
DEV int coh_load_i(const int* p) {
  int v;
  asm volatile("global_load_dword %0, %1, off sc0 sc1\n\ts_waitcnt vmcnt(0)"
               : "=v"(v) : "v"(p) : "memory");
  return v;
}

// ---------------- flag barrier with ONE CACHELINE PER BLOCK ----------------
// flags are at stride 32 ints (128 B): no two writer blocks share a line.
// (R2..R14 packed 32 flags per line -> concurrent same-line write-through
// stores + polls serialized at the coherence point every step.)
#define FSTRIDE 32

DEV void flag_barrier(int* __restrict__ flags, int nblk, int myidx, int gen) {
  asm volatile("s_waitcnt vmcnt(0)" ::: "memory");
  __syncthreads();
  if (threadIdx.x == 0) coh_store_i(flags + (size_t)myidx * FSTRIDE, gen);
  if ((int)threadIdx.x < nblk) {
    int spins = 0;
    while (coh_load_i(flags + (size_t)threadIdx.x * FSTRIDE) < gen) {
      __builtin_amdgcn_s_sleep(4);
      if (++spins > (1 << 21)) break;  // failsafe
    }
  }
  __syncthreads();
}

// one-directional wait: all of another group's flags >= thr.
DEV void wait_group(const int* __restrict__ flags, int nblk, int thr) {
  if ((int)threadIdx.x < nblk) {
    int spins = 0;
    while (coh_load_i(flags + (size_t)threadIdx.x * FSTRIDE) < thr) {
      __builtin_amdgcn_s_sleep(4);
      if (++spins > (1 << 21)) break;
    }
  }
  __syncthreads();
}

// stage 4 waves' scalars -> coalesced dwordx4 write-through
DEV void store_packed_tile4(float* dst_t, const float (*smem)[64], int j0) {
  if (threadIdx.x < 64) {
    int bb = threadIdx.x;
    f32x4 v;
    v.x = smem[0][bb];
    v.y = smem[1][bb];
    v.z = smem[2][bb];
    v.w = smem[3][bb];
    coh_store_f4(dst_t + (size_t)(j0 >> 2) * 256 + bb * 4, v);
  }
}

// ---------------- generic f32 GEMM ----------------
#define GBM 128
#define GBN 128
#define GBK 16

__global__ __launch_bounds__(256) void gemm_nt(
    const float* __restrict__ A, const float* __restrict__ Bt,
    const float* __restrict__ bias, float* __restrict__ C,
    int M, int N, int K, const int* __restrict__ gatherA, int trGI) {
  __shared__ float As[GBK][GBM + 4];
  __shared__ float Bs[GBK][GBN + 4];
  const int bm = blockIdx.y * GBM;
  const int bn = blockIdx.x * GBN;
  const int tid = threadIdx.x;
  const int tx = tid & 15;
  const int ty = tid >> 4;
  float acc[8][8];
  #pragma unroll
  for (int i = 0; i < 8; ++i)
    #pragma unroll
    for (int j = 0; j < 8; ++j) acc[i][j] = 0.f;

  for (int k0 = 0; k0 < K; k0 += GBK) {
    #pragma unroll
    for (int s = 0; s < 2; ++s) {
      int f = tid + s * 256;
      int r = f >> 2, kq = f & 3;
      int row = bm + r;
      float4 v = make_float4(0.f, 0.f, 0.f, 0.f);
      if (row < M) {
        int ar = gatherA ? gatherA[row] : row;
        v = *(const float4*)&A[(size_t)ar * K + k0 + kq * 4];
      }
      As[kq * 4 + 0][r] = v.x;
      As[kq * 4 + 1][r] = v.y;
      As[kq * 4 + 2][r] = v.z;
      As[kq * 4 + 3][r] = v.w;
    }
    #pragma unroll
    for (int s = 0; s < 2; ++s) {
      int f = tid + s * 256;
      int r = f >> 2, kq = f & 3;
      int col = bn + r;
      float4 v = make_float4(0.f, 0.f, 0.f, 0.f);
      if (col < N) v = *(const float4*)&Bt[(size_t)col * K + k0 + kq * 4];
      Bs[kq * 4 + 0][r] = v.x;
      Bs[kq * 4 + 1][r] = v.y;
      Bs[kq * 4 + 2][r] = v.z;
      Bs[kq * 4 + 3][r] = v.w;
    }
    __syncthreads();
    #pragma unroll
    for (int kk = 0; kk < GBK; ++kk) {
      float4 a0 = *(const float4*)&As[kk][ty * 4];
      float4 a1 = *(const float4*)&As[kk][64 + ty * 4];
      float4 b0 = *(const float4*)&Bs[kk][tx * 4];
      float4 b1 = *(const float4*)&Bs[kk][64 + tx * 4];
      float av[8] = {a0.x, a0.y, a0.z, a0.w, a1.x, a1.y, a1.z, a1.w};
      float bv[8] = {b0.x, b0.y, b0.z, b0.w, b1.x, b1.y, b1.z, b1.w};
      #pragma unroll
      for (int i = 0; i < 8; ++i)
        #pragma unroll
        for (int j = 0; j < 8; ++j)
          acc[i][j] = fmaf(av[i], bv[j], acc[i][j]);
    }
    __syncthreads();
  }
  #pragma unroll
  for (int i = 0; i < 8; ++i) {
    int row = bm + ((i < 4) ? (ty * 4 + i) : (64 + ty * 4 + i - 4));
    if (row >= M) continue;
    if (trGI) {
      #pragma unroll
      for (int j = 0; j < 8; ++j) {
        int col = bn + ((j < 4) ? (tx * 4 + j) : (64 + tx * 4 + j - 4));
        if (col >= N) continue;
        float v = acc[i][j] + (bias ? bias[col] : 0.f);
        int bb = row / 48, tt = row - bb * 48;
        C[((size_t)tt * N + col) * 64 + bb] = v;
      }
    } else {
      #pragma unroll
      for (int g = 0; g < 2; ++g) {
        int col0 = bn + g * 64 + tx * 4;
        if (col0 + 3 >= N) continue;
        float4 v;
        v.x = acc[i][g * 4 + 0] + (bias ? bias[col0 + 0] : 0.f);
        v.y = acc[i][g * 4 + 1] + (bias ? bias[col0 + 1] : 0.f);
        v.z = acc[i][g * 4 + 2] + (bias ? bias[col0 + 2] : 0.f);
        v.w = acc[i][g * 4 + 3] + (bias ? bias[col0 + 3] : 0.f);
        *(float4*)&C[(size_t)row * N + col0] = v;
      }
    }
  }
}

// ---------------- misc small kernels ----------------
__global__ void k_transpose(const float* __restrict__ W, float* __restrict__ Wt,
                            int rows, int cols) {
  int idx = blockIdx.x * 256 + threadIdx.x;
  if (idx >= rows * cols) return;
  int r = idx / cols, c = idx % cols;
  Wt[(size_t)c * rows + r] = W[idx];
}

__global__ void k_count_deg(const int* __restrict__ dst, int* __restrict__ deg, int nE) {
  int e = blockIdx.x * 256 + threadIdx.x;
  if (e < nE) atomicAdd(&deg[dst[e]], 1);
}

__global__ __launch_bounds__(1024) void k_scan(const int* __restrict__ deg,
                                               int* __restrict__ off,
                                               int* __restrict__ cursor, int n) {
  __shared__ int tmp[1024];
  __shared__ int carry_s;
  if (threadIdx.x == 0) carry_s = 0;
  __syncthreads();
  for (int base = 0; base < n; base += 1024) {
    int i = base + (int)threadIdx.x;
    int v = (i < n) ? deg[i] : 0;
    tmp[threadIdx.x] = v;
    __syncthreads();
    for (int s = 1; s < 1024; s <<= 1) {
      int t = (threadIdx.x >= (unsigned)s) ? tmp[threadIdx.x - s] : 0;
      __syncthreads();
      tmp[threadIdx.x] += t;
      __syncthreads();
    }
    int incl = tmp[threadIdx.x];
    int base_c = carry_s;
    int excl = incl - v;
    if (i < n) { off[i] = base_c + excl; cursor[i] = base_c + excl; }
    __syncthreads();
    if (threadIdx.x == 1023) carry_s = base_c + incl;
    __syncthreads();
  }
  if (threadIdx.x == 0) off[n] = carry_s;
}

__global__ void k_scatter(const int* __restrict__ dst, int* __restrict__ cursor,
                          int* __restrict__ csr, int nE) {
  int e = blockIdx.x * 256 + threadIdx.x;
  if (e < nE) {
    int pos = atomicAdd(&cursor[dst[e]], 1);
    csr[pos] = e;
  }
}

__global__ void k_alpha(const float* __restrict__ xW, const float* __restrict__ att_src,
                        const float* __restrict__ att_dst, float* __restrict__ as_,
                        float* __restrict__ ad_) {
  int i = blockIdx.x * 256 + threadIdx.x;
  if (i >= 80000) return;
  int n = i >> 2, h = i & 3;
  const float* xr = xW + (size_t)n * 256 + h * 64;
  const float* s = att_src + h * 64;
  const float* d = att_dst + h * 64;
  float a = 0.f, b = 0.f;
  dot2<16>(xr, s, d, a, b);
  as_[i] = a;
  ad_[i] = b;
}

__global__ __launch_bounds__(256) void k_gat_node(
    const float* __restrict__ xW, const float* __restrict__ as_,
    const float* __restrict__ ad_, const int* __restrict__ off,
    const int* __restrict__ csr, const int* __restrict__ esrc,
    const float* __restrict__ eattr, const float* __restrict__ gat_bias,
    float* __restrict__ p) {
  int n = blockIdx.x;
  int h = threadIdx.x >> 6;
  int c = threadIdx.x & 63;
  int s0 = off[n], s1 = off[n + 1];
  float adn = ad_[n * 4 + h];
  float m = -3.0e38f;
  for (int idx = s0; idx < s1; ++idx) {
    int e = csr[idx];
    int s = esrc[e];
    float ev = lrelu(as_[s * 4 + h] + adn);
    m = fmaxf(m, ev);
  }
  float sum = 0.f;
  for (int idx = s0; idx < s1; ++idx) {
    int e = csr[idx];
    int s = esrc[e];
    float ev = lrelu(as_[s * 4 + h] + adn);
    sum += expf(ev - m);
  }
  float acc = 0.f;
  for (int idx = s0; idx < s1; ++idx) {
    int e = csr[idx];
    int s = esrc[e];
    float ev = lrelu(as_[s * 4 + h] + adn);
    float w = expf(ev - m) / (sum + 1e-16f) * eattr[e];
    acc = fmaf(w, xW[(size_t)s * 256 + h * 64 + c], acc);
  }
  p[(size_t)n * 256 + h * 64 + c] = acc + gat_bias[h * 64 + c];
}

__global__ void k_build_X(const float* __restrict__ p, const float* __restrict__ tt,
                          const float* __restrict__ ct, const int* __restrict__ bx,
                          const int* __restrict__ btm, const int* __restrict__ bct,
                          float* __restrict__ X) {
  int idx = blockIdx.x * 256 + threadIdx.x;
  if (idx >= 3072 * 768) return;
  int rl = idx / 768, c = idx % 768;
  float v;
  if (c < 256) v = p[(size_t)bx[rl] * 256 + c];
  else if (c < 512) v = tt[(size_t)btm[rl] * 256 + (c - 256)];
  else v = ct[(size_t)bct[rl] * 256 + (c - 512)];
  X[idx] = v;
}

// ---------------- persistent fused GRU scans (R13 geometry, padded flags) ------
__global__ __launch_bounds__(256, 1) void k_gru_bidir_fused(
    const float* __restrict__ giT_f, const float* __restrict__ giT_b,
    const float* __restrict__ Wh_f, const float* __restrict__ bh_f,
    const float* __restrict__ Wh_b, const float* __restrict__ bh_b,
    float* __restrict__ features, float* __restrict__ hTb,
    int* __restrict__ flags) {
  __shared__ float lds_h[32768];
  __shared__ float smem[4][64];
  int w = threadIdx.x >> 6;
  int b = threadIdx.x & 63;
  int slot = blockIdx.x * 4 + w;
  int dir = slot >> 9;
  int j = slot & 511;
  int j0 = (blockIdx.x * 4) & 511;
  int gbid = blockIdx.x & 127;
  int* gflags = flags + (size_t)dir * 128 * FSTRIDE;
  const float* Wh = dir ? Wh_b : Wh_f;
  const float* bh = dir ? bh_b : bh_f;
  const float* gi = dir ? giT_b : giT_f;
  const float* w0 = Wh + (size_t)j * 512;
  const float* w1 = Wh + (size_t)(512 + j) * 512;
  const float* w2 = Wh + (size_t)(1024 + j) * 512;
  float bhr = bh[j], bhz = bh[512 + j], bhg = bh[1024 + j];
  float* hD = hTb + (size_t)dir * 48 * 32768;
  for (int s = 0; s < 48; ++s) {
    int t = dir ? (47 - s) : s;
    const float* gir = gi + (size_t)t * 98304;
    float giv0 = gir[j * 64 + b];
    float giv1 = gir[(512 + j) * 64 + b];
    float giv2 = gir[(1024 + j) * 64 + b];
    float hr = bhr, hz = bhz, hg = bhg, hprev = 0.f;
    if (s > 0) {
      int tp = dir ? (t + 1) : (t - 1);
      stage_lds<32>(lds_h, hD + (size_t)tp * 32768);
      __syncthreads();
      dotT3_lds<128>(lds_h, b, w0, w1, w2, hr, hz, hg);
      hprev = lds_h[pk(j, b)];
    }
    float hnew = gru_out(giv0, giv1, giv2, hr, hz, hg, hprev);
    smem[w][b] = hnew;
    features[((size_t)(b * 48 + t)) * 1024 + dir * 512 + j] = hnew;
    __syncthreads();
    store_packed_tile4(hD + (size_t)t * 32768, smem, j0);
    flag_barrier(gflags, 128, gbid, s + 1);
  }
}

__global__ __launch_bounds__(256, 1) void k_gru_u_fused(
    const float* __restrict__ giT, const float* __restrict__ Wh,
    const float* __restrict__ bh, float* __restrict__ r_feat,
    float* __restrict__ hU, int* __restrict__ flags) {
  __shared__ float lds_h[32768];
  __shared__ float smem[4][64];
  int w = threadIdx.x >> 6;
  int b = threadIdx.x & 63;
  int j = blockIdx.x * 4 + w;
  int j0 = blockIdx.x * 4;
  const float* w0 = Wh + (size_t)j * 512;
  const float* w1 = Wh + (size_t)(512 + j) * 512;
  const float* w2 = Wh + (size_t)(1024 + j) * 512;
  float bhr = bh[j], bhz = bh[512 + j], bhg = bh[1024 + j];
  for (int s = 0; s < 48; ++s) {
    const float* gir = giT + (size_t)s * 98304;
    float giv0 = gir[j * 64 + b];
    float giv1 = gir[(512 + j) * 64 + b];
    float giv2 = gir[(1024 + j) * 64 + b];
    float hr = bhr, hz = bhz, hg = bhg, hprev = 0.f;
    if (s > 0) {
      stage_lds<32>(lds_h, hU + (size_t)(s - 1) * 32768);
      __syncthreads();
      dotT3_lds<128>(lds_h, b, w0, w1, w2, hr, hz, hg);
      hprev = lds_h[pk(j, b)];
    }
    float hnew = gru_out(giv0, giv1, giv2, hr, hz, hg, hprev);
    smem[w][b] = hnew;
    r_feat[((size_t)(b * 48 + s)) * 512 + j] = hnew;
    __syncthreads();
    store_packed_tile4(hU + (size_t)s * 32768, smem, j0);
    flag_barrier(flags, 128, blockIdx.x, s + 1);
  }
}

// P3: prior double-GRU, producer/consumer.
__global__ __launch_bounds__(256, 1) void k_prior_fused(
    const float* __restrict__ r_post,
    const float* __restrict__ Wp1_i, const float* __restrict__ Wp1_h,
    const float* __restrict__ bp1_i, const float* __restrict__ bp1_h,
    const float* __restrict__ Wp2_i, const float* __restrict__ Wp2_h,
    const float* __restrict__ bp2_i, const float* __restrict__ bp2_h,
    float* __restrict__ h1S, float* __restrict__ h2S,
    float* __restrict__ rT, int* __restrict__ flags) {
  __shared__ float lds_h[32768];
  __shared__ float smem[4][64];
  int w = threadIdx.x >> 6;
  int b = threadIdx.x & 63;
  int cell = blockIdx.x >> 7;
  int gbid = blockIdx.x & 127;
  int slot = blockIdx.x * 4 + w;
  int j = slot & 511;
  int j0 = (blockIdx.x * 4) & 511;
  int* flagsA = flags;
  int* flagsB = flags + (size_t)128 * FSTRIDE;

  if (cell == 0) {
    int tid = gbid * 256 + threadIdx.x;
    for (int x = tid; x < 48 * 64 * 64; x += 32768) {
      int b0 = x & 63;
      int i0 = (x >> 6) & 63;
      int t0 = x >> 12;
      coh_store_f(rT + (size_t)t0 * 4096 + pk(i0, b0),
                  r_post[((size_t)(b0 * 48 + t0)) * 64 + i0]);
    }
    flag_barrier(flagsA, 128, gbid, 1);

    const float* wi0 = Wp1_i + (size_t)j * 64;
    const float* wi1 = Wp1_i + (size_t)(512 + j) * 64;
    const float* wi2 = Wp1_i + (size_t)(1024 + j) * 64;
    const float* wh0 = Wp1_h + (size_t)j * 512;
    const float* wh1 = Wp1_h + (size_t)(512 + j) * 512;
    const float* wh2 = Wp1_h + (size_t)(1024 + j) * 512;
    float bir = bp1_i[j], biz = bp1_i[512 + j], big = bp1_i[1024 + j];
    float bhr = bp1_h[j], bhz = bp1_h[512 + j], bhg = bp1_h[1024 + j];
    for (int k = 0; k < 48; ++k) {
      float ir = bir, iz = biz, ig = big;
      float hr = bhr, hz = bhz, hg = bhg, hprev = 0.f;
      if (k > 0) {
        stage_lds<32>(lds_h, h1S + (size_t)(k - 1) * 32768);
        dotT3p<16>(rT + (size_t)(k - 1) * 4096, b, wi0, wi1, wi2, ir, iz, ig);
        __syncthreads();
        dotT3_lds<128>(lds_h, b, wh0, wh1, wh2, hr, hz, hg);
        hprev = lds_h[pk(j, b)];
      }
      smem[w][b] = gru_out(ir, iz, ig, hr, hz, hg, hprev);
      __syncthreads();
      store_packed_tile4(h1S + (size_t)k * 32768, smem, j0);
      flag_barrier(flagsA, 128, gbid, k + 2);
    }
  } else {
    const float* wi0 = Wp2_i + (size_t)j * 512;
    const float* wi1 = Wp2_i + (size_t)(512 + j) * 512;
    const float* wi2 = Wp2_i + (size_t)(1024 + j) * 512;
    const float* wh0 = Wp2_h + (size_t)j * 512;
    const float* wh1 = Wp2_h + (size_t)(512 + j) * 512;
    const float* wh2 = Wp2_h + (size_t)(1024 + j) * 512;
    float bir = bp2_i[j], biz = bp2_i[512 + j], big = bp2_i[1024 + j];
    float bhr = bp2_h[j], bhz = bp2_h[512 + j], bhg = bp2_h[1024 + j];
    for (int t = 0; t < 48; ++t) {
      wait_group(flagsA, 128, t + 2);
      stage_lds<32>(lds_h, h1S + (size_t)t * 32768);
      __syncthreads();
      float ir = bir, iz = biz, ig = big;
      dotT3_lds<128>(lds_h, b, wi0, wi1, wi2, ir, iz, ig);
      float hr = bhr, hz = bhz, hg = bhg, hprev = 0.f;
      if (t > 0) {
        __syncthreads();
        stage_lds<32>(lds_h, h2S + (size_t)(t - 1) * 32768);
        __syncthreads();
        dotT3_lds<128>(lds_h, b, wh0, wh1, wh2, hr, hz, hg);
        hprev = lds_h[pk(j, b)];
      }
      smem[w][b] = gru_out(ir, iz, ig, hr, hz, hg, hprev);
      __syncthreads();
      store_packed_tile4(h2S + (size_t)t * 32768, smem, j0);
      flag_barrier(flagsB, 128, gbid, t + 1);
    }
  }
}

// ---------------- heads / outputs ----------------
__global__ void k_s_head(const float* __restrict__ features,
                         const float* __restrict__ Ws_m, const float* __restrict__ bs_m,
                         const float* __restrict__ Ws_lv, const float* __restrict__ bs_lv,
                         float* __restrict__ out, uint32_t ka, uint32_t kb) {
  int idx = blockIdx.x * 256 + threadIdx.x;
  if (idx >= 4096) return;
  int i = idx & 63, b = idx >> 6;
  const float* fr = features + ((size_t)(b * 48 + 47)) * 1024;
  const float* bk = features + ((size_t)(b * 48 + 0)) * 1024 + 512;
  const float* wm = Ws_m + (size_t)i * 1024;
  const float* wl = Ws_lv + (size_t)i * 1024;
  float m = 0.f, lv = 0.f;
  dot2<128>(fr, wm, wl, m, lv);
  dot2<128>(bk, wm + 512, wl + 512, m, lv);
  m = lrelu(m + bs_m[i]);
  lv = lrelu(lv + bs_lv[i]);
  float nz = normal_part(ka, kb, (uint32_t)idx);
  out[idx] = m;
  out[4096 + idx] = lv;
  out[8192 + idx] = m + nz * expf(0.5f * lv);
}

__global__ void k_r_head(const float* __restrict__ r_feat,
                         const float* __restrict__ Wr_m, const float* __restrict__ br_m,
                         const float* __restrict__ Wr_lv, const float* __restrict__ br_lv,
                         float* __restrict__ out, uint32_t ka, uint32_t kb) {
  int idx = blockIdx.x * 256 + threadIdx.x;
  if (idx >= 196608) return;
  int i = idx & 63;
  int bt = idx >> 6;
  const float* f = r_feat + (size_t)bt * 512;
  float m = 0.f, lv = 0.f;
  dot2<128>(f, Wr_m + (size_t)i * 512, Wr_lv + (size_t)i * 512, m, lv);
  m += br_m[i];
  lv += br_lv[i];
  float nz = normal_part(ka, kb, (uint32_t)idx);
  out[12288 + idx] = m;
  out[208896 + idx] = lv;
  out[405504 + idx] = m + nz * expf(0.5f * lv);
}

__global__ void k_prior_out(const float* __restrict__ h2S,
                            const float* __restrict__ Wpm, const float* __restrict__ bpm,
                            const float* __restrict__ Wplv, const float* __restrict__ bplv,
                            float* __restrict__ out, uint32_t ka, uint32_t kb) {
  int idx = blockIdx.x * 256 + threadIdx.x;
  if (idx >= 196608) return;
  int i = idx & 63;
  int bt = idx >> 6;
  int b = bt & 63;
  int t = bt >> 6;
  const float4* h4 = (const float4*)(h2S + (size_t)t * 32768);
  const float4* wm4 = (const float4*)(Wpm + (size_t)i * 512);
  const float4* wl4 = (const float4*)(Wplv + (size_t)i * 512);
  float m = 0.f, lv = 0.f;
  #pragma unroll 8
  for (int k4 = 0; k4 < 128; ++k4) {
    float4 hv = h4[k4 * 64 + b];
    m = dot4f(wm4[k4], hv, m);
    lv = dot4f(wl4[k4], hv, lv);
  }
  m += bpm[i];
  lv += bplv[i];
  float ep = normal_part(ka, kb, (uint32_t)idx);
  float rp = m + ep * expf(0.5f * lv);
  size_t o = ((size_t)b * 48 + t) * 64 + i;
  out[602112 + o] = m;
  out[798720 + o] = lv;
  out[995328 + o] = rp;
}

__global__ void k_build_zf(const float* __restrict__ out, float* __restrict__ zf) {
  int idx = blockIdx.x * 256 + threadIdx.x;
  if (idx >= 3072 * 128) return;
  int row = idx >> 7, c = idx & 127;
  float v;
  if (c < 64) v = out[405504 + row * 64 + c];
  else v = out[8192 + (row / 48) * 64 + (c - 64)];
  zf[idx] = v;
}

// ---------------- launcher ----------------
extern "C" void kernel_launch(void* const* d_in, const int* in_sizes, int n_in,
                              void* d_out, int out_size, void* d_ws, size_t ws_size,
                              hipStream_t stream) {
  const int* graph_x = (const int*)d_in[0];
  const int* edge_index = (const int*)d_in[1];
  const float* edge_attr = (const float*)d_in[2];
  const int* batch_x = (const int*)d_in[3];
  const int* batch_time = (const int*)d_in[4];
  const int* batch_cat = (const int*)d_in[5];
  const float* node_emb = (const float*)d_in[8];
  const float* W_gat = (const float*)d_in[9];
  const float* att_src = (const float*)d_in[10];
  const float* att_dst = (const float*)d_in[11];
  const float* gat_bias = (const float*)d_in[12];
  const float* time_table = (const float*)d_in[13];
  const float* cat_table = (const float*)d_in[14];
  const float* W_w = (const float*)d_in[15];
  const float* b_w = (const float*)d_in[16];
  const float* Wi_f = (const float*)d_in[17];
  const float* Wh_f = (const float*)d_in[18];
  const float* bi_f = (const float*)d_in[19];
  const float* bh_f = (const float*)d_in[20];
  const float* Wi_bw = (const float*)d_in[21];
  const float* Wh_bw = (const float*)d_in[22];
  const float* bi_bw = (const float*)d_in[23];
  const float* bh_bw = (const float*)d_in[24];
  const float* Wi_u = (const float*)d_in[25];
  const float* Wh_u = (const float*)d_in[26];
  const float* bi_u = (const float*)d_in[27];
  const float* bh_u = (const float*)d_in[28];
  const float* Ws_m = (const float*)d_in[29];
  const float* bs_m = (const float*)d_in[30];
  const float* Ws_lv = (const float*)d_in[31];
  const float* bs_lv = (const float*)d_in[32];
  const float* Wr_m = (const float*)d_in[33];
  const float* br_m = (const float*)d_in[34];
  const float* Wr_lv = (const float*)d_in[35];
  const float* br_lv = (const float*)d_in[36];
  const float* Wp1_i = (const float*)d_in[37];
  const float* Wp1_h = (const float*)d_in[38];
  const float* bp1_i = (const float*)d_in[39];
  const float* bp1_h = (const float*)d_in[40];
  const float* Wp2_i = (const float*)d_in[41];
  const float* Wp2_h = (const float*)d_in[42];
  const float* bp2_i = (const float*)d_in[43];
  const float* bp2_h = (const float*)d_in[44];
  const float* Wpm = (const float*)d_in[45];
  const float* bpm = (const float*)d_in[46];
  const float* Wplv = (const float*)d_in[47];
  const float* bplv = (const float*)d_in[48];
  const float* Wd = (const float*)d_in[49];
  const float* bd = (const float*)d_in[50];
  float* out = (float*)d_out;

  uint32_t k1a, k1b, k2a, k2b, k3a, k3b;
  tf2x32(0u, 42u, 0u, 0u, &k1a, &k1b);
  tf2x32(0u, 42u, 0u, 1u, &k2a, &k2b);
  tf2x32(0u, 42u, 0u, 2u, &k3a, &k3b);

  float* ws = (float*)d_ws;
  size_t o = 0;
  auto alloc = [&](size_t n) { float* q = ws + o; o += n; return q; };
  float* R1 = alloc(5120000);
  float* R2 = alloc(5120000);
  float* R3 = alloc(4718592);
  float* R4 = alloc(786432);
  float* as_ = alloc(80000);
  float* ad_ = alloc(80000);
  float* Wgt = alloc(65536);
  int* deg = (int*)alloc(20000);
  int* off = (int*)alloc(20001);
  int* cursor = (int*)alloc(20000);
  int* csr = (int*)alloc(320000);
  float* rT = alloc(196608);
  int* flags = (int*)alloc(32768);  // 640 padded flags x 32 ints (128 KB)

  float* xW = R1;
  float* features = R1;
  float* r_feat = R1 + 3145728;
  float* p = R2;
  float* giT_b = R2;
  float* hU = R2;
  float* X = R3;
  float* giT_f = R3;
  float* giT_u = R3;
  float* h1S = R3;
  float* h2S = R3 + 1572864;
  float* ph = R4;
  float* zf = R4;
  float* hTb = out + 1191936;

  const int* esrc = edge_index;
  const int* edst = edge_index + 320000;

  dim3 B(256);

  (void)hipMemsetAsync(deg, 0, 20000 * sizeof(int), stream);
  (void)hipMemsetAsync(flags, 0, 32768 * sizeof(int), stream);

  // ---- GAT ----
  k_transpose<<<dim3(256), B, 0, stream>>>(W_gat, Wgt, 256, 256);
  k_count_deg<<<dim3(1250), B, 0, stream>>>(edst, deg, 320000);
  k_scan<<<dim3(1), dim3(1024), 0, stream>>>(deg, off, cursor, 20000);
  k_scatter<<<dim3(1250), B, 0, stream>>>(edst, cursor, csr, 320000);
  gemm_nt<<<dim3(2, 157), B, 0, stream>>>(node_emb, Wgt, nullptr, xW,
                                          20000, 256, 256, graph_x, 0);
  k_alpha<<<dim3(313), B, 0, stream>>>(xW, att_src, att_dst, as_, ad_);
  k_gat_node<<<dim3(20000), B, 0, stream>>>(xW, as_, ad_, off, csr, esrc,
                                            edge_attr, gat_bias, p);

  // ---- embed concat + W_w ----
  k_build_X<<<dim3(9216), B, 0, stream>>>(p, time_table, cat_table, batch_x,
                                          batch_time, batch_cat, X);
  gemm_nt<<<dim3(2, 24), B, 0, stream>>>(X, W_w, b_w, ph, 3072, 256, 768,
                                         nullptr, 0);

  // ---- gi precompute + fused bidirectional GRU ----
  gemm_nt<<<dim3(12, 24), B, 0, stream>>>(ph, Wi_f, bi_f, giT_f, 3072, 1536, 256,
                                          nullptr, 1);
  gemm_nt<<<dim3(12, 24), B, 0, stream>>>(ph, Wi_bw, bi_bw, giT_b, 3072, 1536, 256,
                                          nullptr, 1);
  k_gru_bidir_fused<<<dim3(256), B, 0, stream>>>(
      giT_f, giT_b, Wh_f, bh_f, Wh_bw, bh_bw, features, hTb, flags);

  // ---- s head ----
  k_s_head<<<dim3(16), B, 0, stream>>>(features, Ws_m, bs_m, Ws_lv, bs_lv,
                                       out, k1a, k1b);

  // ---- r_feat GRU (fused) ----
  gemm_nt<<<dim3(12, 24), B, 0, stream>>>(features, Wi_u, bi_u, giT_u,
                                          3072, 1536, 1024, nullptr, 1);
  k_gru_u_fused<<<dim3(128), B, 0, stream>>>(giT_u, Wh_u, bh_u, r_feat,
                                             hU, flags + 256 * FSTRIDE);

  // ---- r head ----
  k_r_head<<<dim3(768), B, 0, stream>>>(r_feat, Wr_m, br_m, Wr_lv, br_lv,
                                        out, k2a, k2b);

  // ---- prior scan (producer/consumer) ----
  k_prior_fused<<<dim3(256), B, 0, stream>>>(
      out + 405504, Wp1_i, Wp1_h, bp1_i, bp1_h, Wp2_i, Wp2_h, bp2_i, bp2_h,
      h1S, h2S, rT, flags + 384 * FSTRIDE);
  k_prior_out<<<dim3(768), B, 0, stream>>>(h2S, Wpm, bpm, Wplv, bplv,
                                           out, k3a, k3b);

  // ---- recon ----
  k_build_zf<<<dim3(1536), B, 0, stream>>>(out, zf);
  gemm_nt<<<dim3(157, 24), B, 0, stream>>>(zf, Wd, bd, out + 1191936,
                                           3072, 20000, 128, nullptr, 0);
}

// Round 16
// 4637.456 us; speedup vs baseline: 2.2307x; 1.0234x over previous
//
#include <hip/hip_runtime.h>
#include <stdint.h>
#include <stddef.h>

#define DEV __device__ __forceinline__

typedef float f32x4 __attribute__((ext_vector_type(4)));
typedef short bf16x8 __attribute__((ext_vector_type(8)));

// ---------------- threefry2x32 (exact JAX) ----------------
__host__ __device__ inline void tf2x32(uint32_t k0, uint32_t k1,
                                       uint32_t x0, uint32_t x1,
                                       uint32_t* o0, uint32_t* o1) {
  uint32_t ks2 = k0 ^ k1 ^ 0x1BD11BDAu;
  uint32_t ks[3] = {k0, k1, ks2};
  x0 += k0; x1 += k1;
  const uint32_t R[8] = {13u,15u,26u,6u,17u,29u,16u,24u};
  for (int r = 0; r < 5; ++r) {
    const uint32_t* rot = (r & 1) ? (R + 4) : R;
    for (int i = 0; i < 4; ++i) {
      x0 += x1;
      uint32_t d = rot[i];
      x1 = (x1 << d) | (x1 >> (32u - d));
      x1 ^= x0;
    }
    x0 += ks[(r + 1) % 3];
    x1 += ks[(r + 2) % 3] + (uint32_t)(r + 1);
  }
  *o0 = x0; *o1 = x1;
}

DEV float erfinv_approx(float x) {
  float w = -logf((1.0f - x) * (1.0f + x));
  float p;
  if (w < 5.0f) {
    w = w - 2.5f;
    p = 2.81022636e-08f;
    p = fmaf(p, w, 3.43273939e-07f);
    p = fmaf(p, w, -3.5233877e-06f);
    p = fmaf(p, w, -4.39150654e-06f);
    p = fmaf(p, w, 0.00021858087f);
    p = fmaf(p, w, -0.00125372503f);
    p = fmaf(p, w, -0.00417768164f);
    p = fmaf(p, w, 0.246640727f);
    p = fmaf(p, w, 1.50140941f);
  } else {
    w = sqrtf(w) - 3.0f;
    p = -0.000200214257f;
    p = fmaf(p, w, 0.000100950558f);
    p = fmaf(p, w, 0.00134934322f);
    p = fmaf(p, w, -0.00367342844f);
    p = fmaf(p, w, 0.00573950773f);
    p = fmaf(p, w, -0.0076224613f);
    p = fmaf(p, w, 0.00943887047f);
    p = fmaf(p, w, 1.00167406f);
    p = fmaf(p, w, 2.83297682f);
  }
  return p * x;
}

DEV float normal_part(uint32_t ka, uint32_t kb, uint32_t idx) {
  uint32_t b1, b2;
  tf2x32(ka, kb, 0u, idx, &b1, &b2);
  uint32_t bits = b1 ^ b2;
  float f = __uint_as_float((bits >> 9) | 0x3f800000u) - 1.0f;
  const float lo = -0.99999994f;
  float u = f * 2.0f + lo;
  u = fmaxf(lo, u);
  return 1.41421356f * erfinv_approx(u);
}

DEV float lrelu(float x) { return x >= 0.f ? x : 0.2f * x; }
DEV float sigm(float x) { return 1.0f / (1.0f + expf(-x)); }

DEV float gru_out(float ir, float iz, float ig, float hr, float hz, float hg, float hprev) {
  float r = sigm(ir + hr);
  float z = sigm(iz + hz);
  float n = tanhf(ig + r * hg);
  return (1.0f - z) * n + z * hprev;
}

DEV float dot4f(float4 a, float4 b, float acc) {
  return fmaf(a.x, b.x, fmaf(a.y, b.y, fmaf(a.z, b.z, fmaf(a.w, b.w, acc))));
}

template <int K4>
DEV void dot2(const float* __restrict__ h, const float* __restrict__ w0,
              const float* __restrict__ w1, float& a0, float& a1) {
  const float4* h4 = (const float4*)h;
  const float4* p0 = (const float4*)w0;
  const float4* p1 = (const float4*)w1;
  #pragma unroll 4
  for (int k = 0; k < K4; ++k) {
    float4 hv = h4[k];
    float4 v0 = p0[k], v1 = p1[k];
    a0 = dot4f(hv, v0, a0);
    a1 = dot4f(hv, v1, a1);
  }
}

// simple global k-packed 3-gate dot (small K=64 rT dot)
template <int K4>
DEV void dotT3p(const float* __restrict__ hp, int b,
                const float* __restrict__ w0, const float* __restrict__ w1,
                const float* __restrict__ w2, float& a0, float& a1, float& a2) {
  const float4* __restrict__ w04 = (const float4*)w0;
  const float4* __restrict__ w14 = (const float4*)w1;
  const float4* __restrict__ w24 = (const float4*)w2;
  const float4* __restrict__ h4 = (const float4*)hp;
  #pragma unroll
  for (int k4 = 0; k4 < K4; ++k4) {
    float4 hv = h4[k4 * 64 + b];
    a0 = dot4f(w04[k4], hv, a0);
    a1 = dot4f(w14[k4], hv, a1);
    a2 = dot4f(w24[k4], hv, a2);
  }
}

// LDS k-packed 3-gate dot: h tile staged in LDS [k4][b][4].
template <int K4>
DEV void dotT3_lds(const float* __restrict__ hl, int b,
                   const float* __restrict__ w0, const float* __restrict__ w1,
                   const float* __restrict__ w2, float& a0, float& a1, float& a2) {
  const float4* __restrict__ h4 = (const float4*)hl;
  const float4* __restrict__ w04 = (const float4*)w0;
  const float4* __restrict__ w14 = (const float4*)w1;
  const float4* __restrict__ w24 = (const float4*)w2;
  #pragma unroll 8
  for (int k4 = 0; k4 < K4; ++k4) {
    float4 hv = h4[k4 * 64 + b];
    a0 = dot4f(w04[k4], hv, a0);
    a1 = dot4f(w14[k4], hv, a1);
    a2 = dot4f(w24[k4], hv, a2);
  }
}

// cooperative stage: N16 float4 per thread, global -> LDS, 16-deep batches.
template <int N16>
DEV void stage_lds(float* __restrict__ dst, const float* __restrict__ src) {
  const float4* __restrict__ s4 = (const float4*)src;
  float4* __restrict__ d4 = (float4*)dst;
  int tid = threadIdx.x;
  constexpr int CH = (N16 < 16) ? N16 : 16;
  #pragma unroll
  for (int r = 0; r < N16; r += CH) {
    float4 v[CH];
    #pragma unroll
    for (int u = 0; u < CH; ++u) v[u] = s4[(size_t)(r + u) * 256 + tid];
    #pragma unroll
    for (int u = 0; u < CH; ++u) d4[(size_t)(r + u) * 256 + tid] = v[u];
  }
}

// packed element offset for h[k][b] in k-packed layout
DEV size_t pk(int k, int b) { return (size_t)(k >> 2) * 256 + b * 4 + (k & 3); }

// ---------------- write-through (cross-XCD coherent) access, no cache flushes ----
DEV void coh_store_i(int* p, int v) {
  asm volatile("global_store_dword %0, %1, off sc0 sc1" :: "v"(p), "v"(v) : "memory");
}
DEV void coh_store_f(float* p, float v) {
  asm volatile("global_store_dword %0, %1, off sc0 sc1" :: "v"(p), "v"(v) : "memory");
}
DEV void coh_store_f4(float* p, f32x4 v) {
  asm volatile("global_store_dwordx4 %0, %1, off sc0 sc1" :: "v"(p), "v"(v) : "memory");
}
DEV int coh_load_i(const int* p) {
  int v;
  asm volatile("global_load_dword %0, %1, off sc0 sc1\n\ts_waitcnt vmcnt(0)"
               : "=v"(v) : "v"(p) : "memory");
  return v;
}

// ---------------- flag barrier with ONE CACHELINE PER BLOCK ----------------
#define FSTRIDE 32

DEV void flag_barrier(int* __restrict__ flags, int nblk, int myidx, int gen) {
  asm volatile("s_waitcnt vmcnt(0)" ::: "memory");
  __syncthreads();
  if (threadIdx.x == 0) coh_store_i(flags + (size_t)myidx * FSTRIDE, gen);
  if ((int)threadIdx.x < nblk) {
    int spins = 0;
    while (coh_load_i(flags + (size_t)threadIdx.x * FSTRIDE) < gen) {
      __builtin_amdgcn_s_sleep(4);
      if (++spins > (1 << 21)) break;  // failsafe
    }
  }
  __syncthreads();
}

DEV void wait_group(const int* __restrict__ flags, int nblk, int thr) {
  if ((int)threadIdx.x < nblk) {
    int spins = 0;
    while (coh_load_i(flags + (size_t)threadIdx.x * FSTRIDE) < thr) {
      __builtin_amdgcn_s_sleep(4);
      if (++spins > (1 << 21)) break;
    }
  }
  __syncthreads();
}

// stage 4 waves' scalars -> coalesced dwordx4 write-through
DEV void store_packed_tile4(float* dst_t, const float (*smem)[64], int j0) {
  if (threadIdx.x < 64) {
    int bb = threadIdx.x;
    f32x4 v;
    v.x = smem[0][bb];
    v.y = smem[1][bb];
    v.z = smem[2][bb];
    v.w = smem[3][bb];
    coh_store_f4(dst_t + (size_t)(j0 >> 2) * 256 + bb * 4, v);
  }
}

// ---------------- generic f32 GEMM ----------------
#define GBM 128
#define GBN 128
#define GBK 16

__global__ __launch_bounds__(256) void gemm_nt(
    const float* __restrict__ A, const float* __restrict__ Bt,
    const float* __restrict__ bias, float* __restrict__ C,
    int M, int N, int K, const int* __restrict__ gatherA, int trGI) {
  __shared__ float As[GBK][GBM + 4];
  __shared__ float Bs[GBK][GBN + 4];
  const int bm = blockIdx.y * GBM;
  const int bn = blockIdx.x * GBN;
  const int tid = threadIdx.x;
  const int tx = tid & 15;
  const int ty = tid >> 4;
  float acc[8][8];
  #pragma unroll
  for (int i = 0; i < 8; ++i)
    #pragma unroll
    for (int j = 0; j < 8; ++j) acc[i][j] = 0.f;

  for (int k0 = 0; k0 < K; k0 += GBK) {
    #pragma unroll
    for (int s = 0; s < 2; ++s) {
      int f = tid + s * 256;
      int r = f >> 2, kq = f & 3;
      int row = bm + r;
      float4 v = make_float4(0.f, 0.f, 0.f, 0.f);
      if (row < M) {
        int ar = gatherA ? gatherA[row] : row;
        v = *(const float4*)&A[(size_t)ar * K + k0 + kq * 4];
      }
      As[kq * 4 + 0][r] = v.x;
      As[kq * 4 + 1][r] = v.y;
      As[kq * 4 + 2][r] = v.z;
      As[kq * 4 + 3][r] = v.w;
    }
    #pragma unroll
    for (int s = 0; s < 2; ++s) {
      int f = tid + s * 256;
      int r = f >> 2, kq = f & 3;
      int col = bn + r;
      float4 v = make_float4(0.f, 0.f, 0.f, 0.f);
      if (col < N) v = *(const float4*)&Bt[(size_t)col * K + k0 + kq * 4];
      Bs[kq * 4 + 0][r] = v.x;
      Bs[kq * 4 + 1][r] = v.y;
      Bs[kq * 4 + 2][r] = v.z;
      Bs[kq * 4 + 3][r] = v.w;
    }
    __syncthreads();
    #pragma unroll
    for (int kk = 0; kk < GBK; ++kk) {
      float4 a0 = *(const float4*)&As[kk][ty * 4];
      float4 a1 = *(const float4*)&As[kk][64 + ty * 4];
      float4 b0 = *(const float4*)&Bs[kk][tx * 4];
      float4 b1 = *(const float4*)&Bs[kk][64 + tx * 4];
      float av[8] = {a0.x, a0.y, a0.z, a0.w, a1.x, a1.y, a1.z, a1.w};
      float bv[8] = {b0.x, b0.y, b0.z, b0.w, b1.x, b1.y, b1.z, b1.w};
      #pragma unroll
      for (int i = 0; i < 8; ++i)
        #pragma unroll
        for (int j = 0; j < 8; ++j)
          acc[i][j] = fmaf(av[i], bv[j], acc[i][j]);
    }
    __syncthreads();
  }
  #pragma unroll
  for (int i = 0; i < 8; ++i) {
    int row = bm + ((i < 4) ? (ty * 4 + i) : (64 + ty * 4 + i - 4));
    if (row >= M) continue;
    if (trGI) {
      #pragma unroll
      for (int j = 0; j < 8; ++j) {
        int col = bn + ((j < 4) ? (tx * 4 + j) : (64 + tx * 4 + j - 4));
        if (col >= N) continue;
        float v = acc[i][j] + (bias ? bias[col] : 0.f);
        int bb = row / 48, tt = row - bb * 48;
        C[((size_t)tt * N + col) * 64 + bb] = v;
      }
    } else {
      #pragma unroll
      for (int g = 0; g < 2; ++g) {
        int col0 = bn + g * 64 + tx * 4;
        if (col0 + 3 >= N) continue;
        float4 v;
        v.x = acc[i][g * 4 + 0] + (bias ? bias[col0 + 0] : 0.f);
        v.y = acc[i][g * 4 + 1] + (bias ? bias[col0 + 1] : 0.f);
        v.z = acc[i][g * 4 + 2] + (bias ? bias[col0 + 2] : 0.f);
        v.w = acc[i][g * 4 + 3] + (bias ? bias[col0 + 3] : 0.f);
        *(float4*)&C[(size_t)row * N + col0] = v;
      }
    }
  }
}

// ---------------- bf16 conversion + MFMA GEMM (recon) ----------------
__global__ void k_f32_to_bf16(const float* __restrict__ src,
                              unsigned short* __restrict__ dst, int n) {
  int i = blockIdx.x * 256 + threadIdx.x;
  if (i >= n) return;
  uint32_t u = __float_as_uint(src[i]);
  uint32_t r = (u + 0x7fffu + ((u >> 16) & 1u)) >> 16;
  dst[i] = (unsigned short)r;
}

// C[M,N] = A16[M,K] @ B16[N,K]^T + bias, K=128, bf16 MFMA 16x16x32.
// grid (M/128, N/128up); block 256 = 4 waves in 2x2; wave tile 64x64.
__global__ __launch_bounds__(256) void gemm_bf16_mfma(
    const unsigned short* __restrict__ A16, const unsigned short* __restrict__ B16,
    const float* __restrict__ bias, float* __restrict__ C,
    int M, int N, int K) {
  int bm = blockIdx.x * 128;
  int bn = blockIdx.y * 128;
  int wave = threadIdx.x >> 6;
  int lane = threadIdx.x & 63;
  int wm = (wave & 1) * 64;
  int wn = (wave >> 1) * 64;
  int l15 = lane & 15;
  int kg = lane >> 4;
  f32x4 acc[4][4];
  #pragma unroll
  for (int mi = 0; mi < 4; ++mi)
    #pragma unroll
    for (int ni = 0; ni < 4; ++ni)
      acc[mi][ni] = (f32x4){0.f, 0.f, 0.f, 0.f};

  for (int kk = 0; kk < K; kk += 32) {
    bf16x8 afrag[4], bfrag[4];
    #pragma unroll
    for (int mi = 0; mi < 4; ++mi) {
      int row = bm + wm + mi * 16 + l15;
      afrag[mi] = *(const bf16x8*)&A16[(size_t)row * K + kk + kg * 8];
    }
    #pragma unroll
    for (int ni = 0; ni < 4; ++ni) {
      int col = bn + wn + ni * 16 + l15;
      if (col >= N) col = N - 1;  // clamp (stores guarded)
      bfrag[ni] = *(const bf16x8*)&B16[(size_t)col * K + kk + kg * 8];
    }
    #pragma unroll
    for (int mi = 0; mi < 4; ++mi)
      #pragma unroll
      for (int ni = 0; ni < 4; ++ni)
        acc[mi][ni] = __builtin_amdgcn_mfma_f32_16x16x32_bf16(
            afrag[mi], bfrag[ni], acc[mi][ni], 0, 0, 0);
  }
  // C/D: col = lane&15, row = (lane>>4)*4 + reg  [m89-verified]
  #pragma unroll
  for (int mi = 0; mi < 4; ++mi) {
    #pragma unroll
    for (int ni = 0; ni < 4; ++ni) {
      int col = bn + wn + ni * 16 + l15;
      if (col >= N) continue;
      int rowb = bm + wm + mi * 16 + kg * 4;
      float bv = bias[col];
      #pragma unroll
      for (int r = 0; r < 4; ++r)
        C[(size_t)(rowb + r) * N + col] = acc[mi][ni][r] + bv;
    }
  }
}

// ---------------- misc small kernels ----------------
__global__ void k_transpose(const float* __restrict__ W, float* __restrict__ Wt,
                            int rows, int cols) {
  int idx = blockIdx.x * 256 + threadIdx.x;
  if (idx >= rows * cols) return;
  int r = idx / cols, c = idx % cols;
  Wt[(size_t)c * rows + r] = W[idx];
}

__global__ void k_count_deg(const int* __restrict__ dst, int* __restrict__ deg, int nE) {
  int e = blockIdx.x * 256 + threadIdx.x;
  if (e < nE) atomicAdd(&deg[dst[e]], 1);
}

__global__ __launch_bounds__(1024) void k_scan(const int* __restrict__ deg,
                                               int* __restrict__ off,
                                               int* __restrict__ cursor, int n) {
  __shared__ int tmp[1024];
  __shared__ int carry_s;
  if (threadIdx.x == 0) carry_s = 0;
  __syncthreads();
  for (int base = 0; base < n; base += 1024) {
    int i = base + (int)threadIdx.x;
    int v = (i < n) ? deg[i] : 0;
    tmp[threadIdx.x] = v;
    __syncthreads();
    for (int s = 1; s < 1024; s <<= 1) {
      int t = (threadIdx.x >= (unsigned)s) ? tmp[threadIdx.x - s] : 0;
      __syncthreads();
      tmp[threadIdx.x] += t;
      __syncthreads();
    }
    int incl = tmp[threadIdx.x];
    int base_c = carry_s;
    int excl = incl - v;
    if (i < n) { off[i] = base_c + excl; cursor[i] = base_c + excl; }
    __syncthreads();
    if (threadIdx.x == 1023) carry_s = base_c + incl;
    __syncthreads();
  }
  if (threadIdx.x == 0) off[n] = carry_s;
}

__global__ void k_scatter(const int* __restrict__ dst, int* __restrict__ cursor,
                          int* __restrict__ csr, int nE) {
  int e = blockIdx.x * 256 + threadIdx.x;
  if (e < nE) {
    int pos = atomicAdd(&cursor[dst[e]], 1);
    csr[pos] = e;
  }
}

__global__ void k_alpha(const float* __restrict__ xW, const float* __restrict__ att_src,
                        const float* __restrict__ att_dst, float* __restrict__ as_,
                        float* __restrict__ ad_) {
  int i = blockIdx.x * 256 + threadIdx.x;
  if (i >= 80000) return;
  int n = i >> 2, h = i & 3;
  const float* xr = xW + (size_t)n * 256 + h * 64;
  const float* s = att_src + h * 64;
  const float* d = att_dst + h * 64;
  float a = 0.f, b = 0.f;
  dot2<16>(xr, s, d, a, b);
  as_[i] = a;
  ad_[i] = b;
}

__global__ __launch_bounds__(256) void k_gat_node(
    const float* __restrict__ xW, const float* __restrict__ as_,
    const float* __restrict__ ad_, const int* __restrict__ off,
    const int* __restrict__ csr, const int* __restrict__ esrc,
    const float* __restrict__ eattr, const float* __restrict__ gat_bias,
    float* __restrict__ p) {
  int n = blockIdx.x;
  int h = threadIdx.x >> 6;
  int c = threadIdx.x & 63;
  int s0 = off[n], s1 = off[n + 1];
  float adn = ad_[n * 4 + h];
  float m = -3.0e38f;
  for (int idx = s0; idx < s1; ++idx) {
    int e = csr[idx];
    int s = esrc[e];
    float ev = lrelu(as_[s * 4 + h] + adn);
    m = fmaxf(m, ev);
  }
  float sum = 0.f;
  for (int idx = s0; idx < s1; ++idx) {
    int e = csr[idx];
    int s = esrc[e];
    float ev = lrelu(as_[s * 4 + h] + adn);
    sum += expf(ev - m);
  }
  float acc = 0.f;
  for (int idx = s0; idx < s1; ++idx) {
    int e = csr[idx];
    int s = esrc[e];
    float ev = lrelu(as_[s * 4 + h] + adn);
    float w = expf(ev - m) / (sum + 1e-16f) * eattr[e];
    acc = fmaf(w, xW[(size_t)s * 256 + h * 64 + c], acc);
  }
  p[(size_t)n * 256 + h * 64 + c] = acc + gat_bias[h * 64 + c];
}

__global__ void k_build_X(const float* __restrict__ p, const float* __restrict__ tt,
                          const float* __restrict__ ct, const int* __restrict__ bx,
                          const int* __restrict__ btm, const int* __restrict__ bct,
                          float* __restrict__ X) {
  int idx = blockIdx.x * 256 + threadIdx.x;
  if (idx >= 3072 * 768) return;
  int rl = idx / 768, c = idx % 768;
  float v;
  if (c < 256) v = p[(size_t)bx[rl] * 256 + c];
  else if (c < 512) v = tt[(size_t)btm[rl] * 256 + (c - 256)];
  else v = ct[(size_t)bct[rl] * 256 + (c - 512)];
  X[idx] = v;
}

// ---------------- persistent fused GRU scans (R15 structure) ----------------
__global__ __launch_bounds__(256, 1) void k_gru_bidir_fused(
    const float* __restrict__ giT_f, const float* __restrict__ giT_b,
    const float* __restrict__ Wh_f, const float* __restrict__ bh_f,
    const float* __restrict__ Wh_b, const float* __restrict__ bh_b,
    float* __restrict__ features, float* __restrict__ hTb,
    int* __restrict__ flags) {
  __shared__ float lds_h[32768];
  __shared__ float smem[4][64];
  int w = threadIdx.x >> 6;
  int b = threadIdx.x & 63;
  int slot = blockIdx.x * 4 + w;
  int dir = slot >> 9;
  int j = slot & 511;
  int j0 = (blockIdx.x * 4) & 511;
  int gbid = blockIdx.x & 127;
  int* gflags = flags + (size_t)dir * 128 * FSTRIDE;
  const float* Wh = dir ? Wh_b : Wh_f;
  const float* bh = dir ? bh_b : bh_f;
  const float* gi = dir ? giT_b : giT_f;
  const float* w0 = Wh + (size_t)j * 512;
  const float* w1 = Wh + (size_t)(512 + j) * 512;
  const float* w2 = Wh + (size_t)(1024 + j) * 512;
  float bhr = bh[j], bhz = bh[512 + j], bhg = bh[1024 + j];
  float* hD = hTb + (size_t)dir * 48 * 32768;
  for (int s = 0; s < 48; ++s) {
    int t = dir ? (47 - s) : s;
    const float* gir = gi + (size_t)t * 98304;
    float giv0 = gir[j * 64 + b];
    float giv1 = gir[(512 + j) * 64 + b];
    float giv2 = gir[(1024 + j) * 64 + b];
    float hr = bhr, hz = bhz, hg = bhg, hprev = 0.f;
    if (s > 0) {
      int tp = dir ? (t + 1) : (t - 1);
      stage_lds<32>(lds_h, hD + (size_t)tp * 32768);
      __syncthreads();
      dotT3_lds<128>(lds_h, b, w0, w1, w2, hr, hz, hg);
      hprev = lds_h[pk(j, b)];
    }
    float hnew = gru_out(giv0, giv1, giv2, hr, hz, hg, hprev);
    smem[w][b] = hnew;
    features[((size_t)(b * 48 + t)) * 1024 + dir * 512 + j] = hnew;
    __syncthreads();
    store_packed_tile4(hD + (size_t)t * 32768, smem, j0);
    flag_barrier(gflags, 128, gbid, s + 1);
  }
}

__global__ __launch_bounds__(256, 1) void k_gru_u_fused(
    const float* __restrict__ giT, const float* __restrict__ Wh,
    const float* __restrict__ bh, float* __restrict__ r_feat,
    float* __restrict__ hU, int* __restrict__ flags) {
  __shared__ float lds_h[32768];
  __shared__ float smem[4][64];
  int w = threadIdx.x >> 6;
  int b = threadIdx.x & 63;
  int j = blockIdx.x * 4 + w;
  int j0 = blockIdx.x * 4;
  const float* w0 = Wh + (size_t)j * 512;
  const float* w1 = Wh + (size_t)(512 + j) * 512;
  const float* w2 = Wh + (size_t)(1024 + j) * 512;
  float bhr = bh[j], bhz = bh[512 + j], bhg = bh[1024 + j];
  for (int s = 0; s < 48; ++s) {
    const float* gir = giT + (size_t)s * 98304;
    float giv0 = gir[j * 64 + b];
    float giv1 = gir[(512 + j) * 64 + b];
    float giv2 = gir[(1024 + j) * 64 + b];
    float hr = bhr, hz = bhz, hg = bhg, hprev = 0.f;
    if (s > 0) {
      stage_lds<32>(lds_h, hU + (size_t)(s - 1) * 32768);
      __syncthreads();
      dotT3_lds<128>(lds_h, b, w0, w1, w2, hr, hz, hg);
      hprev = lds_h[pk(j, b)];
    }
    float hnew = gru_out(giv0, giv1, giv2, hr, hz, hg, hprev);
    smem[w][b] = hnew;
    r_feat[((size_t)(b * 48 + s)) * 512 + j] = hnew;
    __syncthreads();
    store_packed_tile4(hU + (size_t)s * 32768, smem, j0);
    flag_barrier(flags, 128, blockIdx.x, s + 1);
  }
}

__global__ __launch_bounds__(256, 1) void k_prior_fused(
    const float* __restrict__ r_post,
    const float* __restrict__ Wp1_i, const float* __restrict__ Wp1_h,
    const float* __restrict__ bp1_i, const float* __restrict__ bp1_h,
    const float* __restrict__ Wp2_i, const float* __restrict__ Wp2_h,
    const float* __restrict__ bp2_i, const float* __restrict__ bp2_h,
    float* __restrict__ h1S, float* __restrict__ h2S,
    float* __restrict__ rT, int* __restrict__ flags) {
  __shared__ float lds_h[32768];
  __shared__ float smem[4][64];
  int w = threadIdx.x >> 6;
  int b = threadIdx.x & 63;
  int cell = blockIdx.x >> 7;
  int gbid = blockIdx.x & 127;
  int slot = blockIdx.x * 4 + w;
  int j = slot & 511;
  int j0 = (blockIdx.x * 4) & 511;
  int* flagsA = flags;
  int* flagsB = flags + (size_t)128 * FSTRIDE;

  if (cell == 0) {
    int tid = gbid * 256 + threadIdx.x;
    for (int x = tid; x < 48 * 64 * 64; x += 32768) {
      int b0 = x & 63;
      int i0 = (x >> 6) & 63;
      int t0 = x >> 12;
      coh_store_f(rT + (size_t)t0 * 4096 + pk(i0, b0),
                  r_post[((size_t)(b0 * 48 + t0)) * 64 + i0]);
    }
    flag_barrier(flagsA, 128, gbid, 1);

    const float* wi0 = Wp1_i + (size_t)j * 64;
    const float* wi1 = Wp1_i + (size_t)(512 + j) * 64;
    const float* wi2 = Wp1_i + (size_t)(1024 + j) * 64;
    const float* wh0 = Wp1_h + (size_t)j * 512;
    const float* wh1 = Wp1_h + (size_t)(512 + j) * 512;
    const float* wh2 = Wp1_h + (size_t)(1024 + j) * 512;
    float bir = bp1_i[j], biz = bp1_i[512 + j], big = bp1_i[1024 + j];
    float bhr = bp1_h[j], bhz = bp1_h[512 + j], bhg = bp1_h[1024 + j];
    for (int k = 0; k < 48; ++k) {
      float ir = bir, iz = biz, ig = big;
      float hr = bhr, hz = bhz, hg = bhg, hprev = 0.f;
      if (k > 0) {
        stage_lds<32>(lds_h, h1S + (size_t)(k - 1) * 32768);
        dotT3p<16>(rT + (size_t)(k - 1) * 4096, b, wi0, wi1, wi2, ir, iz, ig);
        __syncthreads();
        dotT3_lds<128>(lds_h, b, wh0, wh1, wh2, hr, hz, hg);
        hprev = lds_h[pk(j, b)];
      }
      smem[w][b] = gru_out(ir, iz, ig, hr, hz, hg, hprev);
      __syncthreads();
      store_packed_tile4(h1S + (size_t)k * 32768, smem, j0);
      flag_barrier(flagsA, 128, gbid, k + 2);
    }
  } else {
    const float* wi0 = Wp2_i + (size_t)j * 512;
    const float* wi1 = Wp2_i + (size_t)(512 + j) * 512;
    const float* wi2 = Wp2_i + (size_t)(1024 + j) * 512;
    const float* wh0 = Wp2_h + (size_t)j * 512;
    const float* wh1 = Wp2_h + (size_t)(512 + j) * 512;
    const float* wh2 = Wp2_h + (size_t)(1024 + j) * 512;
    float bir = bp2_i[j], biz = bp2_i[512 + j], big = bp2_i[1024 + j];
    float bhr = bp2_h[j], bhz = bp2_h[512 + j], bhg = bp2_h[1024 + j];
    for (int t = 0; t < 48; ++t) {
      wait_group(flagsA, 128, t + 2);
      stage_lds<32>(lds_h, h1S + (size_t)t * 32768);
      __syncthreads();
      float ir = bir, iz = biz, ig = big;
      dotT3_lds<128>(lds_h, b, wi0, wi1, wi2, ir, iz, ig);
      float hr = bhr, hz = bhz, hg = bhg, hprev = 0.f;
      if (t > 0) {
        __syncthreads();
        stage_lds<32>(lds_h, h2S + (size_t)(t - 1) * 32768);
        __syncthreads();
        dotT3_lds<128>(lds_h, b, wh0, wh1, wh2, hr, hz, hg);
        hprev = lds_h[pk(j, b)];
      }
      smem[w][b] = gru_out(ir, iz, ig, hr, hz, hg, hprev);
      __syncthreads();
      store_packed_tile4(h2S + (size_t)t * 32768, smem, j0);
      flag_barrier(flagsB, 128, gbid, t + 1);
    }
  }
}

// ---------------- heads / outputs ----------------
__global__ void k_s_head(const float* __restrict__ features,
                         const float* __restrict__ Ws_m, const float* __restrict__ bs_m,
                         const float* __restrict__ Ws_lv, const float* __restrict__ bs_lv,
                         float* __restrict__ out, uint32_t ka, uint32_t kb) {
  int idx = blockIdx.x * 256 + threadIdx.x;
  if (idx >= 4096) return;
  int i = idx & 63, b = idx >> 6;
  const float* fr = features + ((size_t)(b * 48 + 47)) * 1024;
  const float* bk = features + ((size_t)(b * 48 + 0)) * 1024 + 512;
  const float* wm = Ws_m + (size_t)i * 1024;
  const float* wl = Ws_lv + (size_t)i * 1024;
  float m = 0.f, lv = 0.f;
  dot2<128>(fr, wm, wl, m, lv);
  dot2<128>(bk, wm + 512, wl + 512, m, lv);
  m = lrelu(m + bs_m[i]);
  lv = lrelu(lv + bs_lv[i]);
  float nz = normal_part(ka, kb, (uint32_t)idx);
  out[idx] = m;
  out[4096 + idx] = lv;
  out[8192 + idx] = m + nz * expf(0.5f * lv);
}

__global__ void k_r_head(const float* __restrict__ r_feat,
                         const float* __restrict__ Wr_m, const float* __restrict__ br_m,
                         const float* __restrict__ Wr_lv, const float* __restrict__ br_lv,
                         float* __restrict__ out, uint32_t ka, uint32_t kb) {
  int idx = blockIdx.x * 256 + threadIdx.x;
  if (idx >= 196608) return;
  int i = idx & 63;
  int bt = idx >> 6;
  const float* f = r_feat + (size_t)bt * 512;
  float m = 0.f, lv = 0.f;
  dot2<128>(f, Wr_m + (size_t)i * 512, Wr_lv + (size_t)i * 512, m, lv);
  m += br_m[i];
  lv += br_lv[i];
  float nz = normal_part(ka, kb, (uint32_t)idx);
  out[12288 + idx] = m;
  out[208896 + idx] = lv;
  out[405504 + idx] = m + nz * expf(0.5f * lv);
}

__global__ void k_prior_out(const float* __restrict__ h2S,
                            const float* __restrict__ Wpm, const float* __restrict__ bpm,
                            const float* __restrict__ Wplv, const float* __restrict__ bplv,
                            float* __restrict__ out, uint32_t ka, uint32_t kb) {
  int idx = blockIdx.x * 256 + threadIdx.x;
  if (idx >= 196608) return;
  int i = idx & 63;
  int bt = idx >> 6;
  int b = bt & 63;
  int t = bt >> 6;
  const float4* h4 = (const float4*)(h2S + (size_t)t * 32768);
  const float4* wm4 = (const float4*)(Wpm + (size_t)i * 512);
  const float4* wl4 = (const float4*)(Wplv + (size_t)i * 512);
  float m = 0.f, lv = 0.f;
  #pragma unroll 8
  for (int k4 = 0; k4 < 128; ++k4) {
    float4 hv = h4[k4 * 64 + b];
    m = dot4f(wm4[k4], hv, m);
    lv = dot4f(wl4[k4], hv, lv);
  }
  m += bpm[i];
  lv += bplv[i];
  float ep = normal_part(ka, kb, (uint32_t)idx);
  float rp = m + ep * expf(0.5f * lv);
  size_t o = ((size_t)b * 48 + t) * 64 + i;
  out[602112 + o] = m;
  out[798720 + o] = lv;
  out[995328 + o] = rp;
}

__global__ void k_build_zf(const float* __restrict__ out, float* __restrict__ zf) {
  int idx = blockIdx.x * 256 + threadIdx.x;
  if (idx >= 3072 * 128) return;
  int row = idx >> 7, c = idx & 127;
  float v;
  if (c < 64) v = out[405504 + row * 64 + c];
  else v = out[8192 + (row / 48) * 64 + (c - 64)];
  zf[idx] = v;
}

// ---------------- launcher ----------------
extern "C" void kernel_launch(void* const* d_in, const int* in_sizes, int n_in,
                              void* d_out, int out_size, void* d_ws, size_t ws_size,
                              hipStream_t stream) {
  const int* graph_x = (const int*)d_in[0];
  const int* edge_index = (const int*)d_in[1];
  const float* edge_attr = (const float*)d_in[2];
  const int* batch_x = (const int*)d_in[3];
  const int* batch_time = (const int*)d_in[4];
  const int* batch_cat = (const int*)d_in[5];
  const float* node_emb = (const float*)d_in[8];
  const float* W_gat = (const float*)d_in[9];
  const float* att_src = (const float*)d_in[10];
  const float* att_dst = (const float*)d_in[11];
  const float* gat_bias = (const float*)d_in[12];
  const float* time_table = (const float*)d_in[13];
  const float* cat_table = (const float*)d_in[14];
  const float* W_w = (const float*)d_in[15];
  const float* b_w = (const float*)d_in[16];
  const float* Wi_f = (const float*)d_in[17];
  const float* Wh_f = (const float*)d_in[18];
  const float* bi_f = (const float*)d_in[19];
  const float* bh_f = (const float*)d_in[20];
  const float* Wi_bw = (const float*)d_in[21];
  const float* Wh_bw = (const float*)d_in[22];
  const float* bi_bw = (const float*)d_in[23];
  const float* bh_bw = (const float*)d_in[24];
  const float* Wi_u = (const float*)d_in[25];
  const float* Wh_u = (const float*)d_in[26];
  const float* bi_u = (const float*)d_in[27];
  const float* bh_u = (const float*)d_in[28];
  const float* Ws_m = (const float*)d_in[29];
  const float* bs_m = (const float*)d_in[30];
  const float* Ws_lv = (const float*)d_in[31];
  const float* bs_lv = (const float*)d_in[32];
  const float* Wr_m = (const float*)d_in[33];
  const float* br_m = (const float*)d_in[34];
  const float* Wr_lv = (const float*)d_in[35];
  const float* br_lv = (const float*)d_in[36];
  const float* Wp1_i = (const float*)d_in[37];
  const float* Wp1_h = (const float*)d_in[38];
  const float* bp1_i = (const float*)d_in[39];
  const float* bp1_h = (const float*)d_in[40];
  const float* Wp2_i = (const float*)d_in[41];
  const float* Wp2_h = (const float*)d_in[42];
  const float* bp2_i = (const float*)d_in[43];
  const float* bp2_h = (const float*)d_in[44];
  const float* Wpm = (const float*)d_in[45];
  const float* bpm = (const float*)d_in[46];
  const float* Wplv = (const float*)d_in[47];
  const float* bplv = (const float*)d_in[48];
  const float* Wd = (const float*)d_in[49];
  const float* bd = (const float*)d_in[50];
  float* out = (float*)d_out;

  uint32_t k1a, k1b, k2a, k2b, k3a, k3b;
  tf2x32(0u, 42u, 0u, 0u, &k1a, &k1b);
  tf2x32(0u, 42u, 0u, 1u, &k2a, &k2b);
  tf2x32(0u, 42u, 0u, 2u, &k3a, &k3b);

  float* ws = (float*)d_ws;
  size_t o = 0;
  auto alloc = [&](size_t n) { float* q = ws + o; o += n; return q; };
  float* R1 = alloc(5120000);
  float* R2 = alloc(5120000);
  float* R3 = alloc(4718592);
  float* R4 = alloc(786432);
  float* as_ = alloc(80000);
  float* ad_ = alloc(80000);
  float* Wgt = alloc(65536);
  int* deg = (int*)alloc(20000);
  int* off = (int*)alloc(20001);
  int* cursor = (int*)alloc(20000);
  int* csr = (int*)alloc(320000);
  float* rT = alloc(196608);
  int* flags = (int*)alloc(32768);  // 640 padded flags x 32 ints

  float* xW = R1;
  float* features = R1;
  float* r_feat = R1 + 3145728;
  float* p = R2;
  float* giT_b = R2;
  float* hU = R2;
  float* X = R3;
  float* giT_f = R3;
  float* giT_u = R3;
  float* h1S = R3;
  float* h2S = R3 + 1572864;
  float* ph = R4;
  float* zf = R4;
  unsigned short* Wd16 = (unsigned short*)R2;          // hU dead after u-scan
  unsigned short* zf16 = (unsigned short*)(R4 + 458752);
  float* hTb = out + 1191936;

  const int* esrc = edge_index;
  const int* edst = edge_index + 320000;

  dim3 B(256);

  (void)hipMemsetAsync(deg, 0, 20000 * sizeof(int), stream);
  (void)hipMemsetAsync(flags, 0, 32768 * sizeof(int), stream);

  // ---- GAT ----
  k_transpose<<<dim3(256), B, 0, stream>>>(W_gat, Wgt, 256, 256);
  k_count_deg<<<dim3(1250), B, 0, stream>>>(edst, deg, 320000);
  k_scan<<<dim3(1), dim3(1024), 0, stream>>>(deg, off, cursor, 20000);
  k_scatter<<<dim3(1250), B, 0, stream>>>(edst, cursor, csr, 320000);
  gemm_nt<<<dim3(2, 157), B, 0, stream>>>(node_emb, Wgt, nullptr, xW,
                                          20000, 256, 256, graph_x, 0);
  k_alpha<<<dim3(313), B, 0, stream>>>(xW, att_src, att_dst, as_, ad_);
  k_gat_node<<<dim3(20000), B, 0, stream>>>(xW, as_, ad_, off, csr, esrc,
                                            edge_attr, gat_bias, p);

  // ---- embed concat + W_w ----
  k_build_X<<<dim3(9216), B, 0, stream>>>(p, time_table, cat_table, batch_x,
                                          batch_time, batch_cat, X);
  gemm_nt<<<dim3(2, 24), B, 0, stream>>>(X, W_w, b_w, ph, 3072, 256, 768,
                                         nullptr, 0);

  // ---- gi precompute + fused bidirectional GRU ----
  gemm_nt<<<dim3(12, 24), B, 0, stream>>>(ph, Wi_f, bi_f, giT_f, 3072, 1536, 256,
                                          nullptr, 1);
  gemm_nt<<<dim3(12, 24), B, 0, stream>>>(ph, Wi_bw, bi_bw, giT_b, 3072, 1536, 256,
                                          nullptr, 1);
  k_gru_bidir_fused<<<dim3(256), B, 0, stream>>>(
      giT_f, giT_b, Wh_f, bh_f, Wh_bw, bh_bw, features, hTb, flags);

  // ---- s head ----
  k_s_head<<<dim3(16), B, 0, stream>>>(features, Ws_m, bs_m, Ws_lv, bs_lv,
                                       out, k1a, k1b);

  // ---- r_feat GRU (fused) ----
  gemm_nt<<<dim3(12, 24), B, 0, stream>>>(features, Wi_u, bi_u, giT_u,
                                          3072, 1536, 1024, nullptr, 1);
  k_gru_u_fused<<<dim3(128), B, 0, stream>>>(giT_u, Wh_u, bh_u, r_feat,
                                             hU, flags + 256 * FSTRIDE);

  // ---- Wd -> bf16 (hU region now dead) ----
  k_f32_to_bf16<<<dim3(10000), B, 0, stream>>>(Wd, Wd16, 20000 * 128);

  // ---- r head ----
  k_r_head<<<dim3(768), B, 0, stream>>>(r_feat, Wr_m, br_m, Wr_lv, br_lv,
                                        out, k2a, k2b);

  // ---- prior scan (producer/consumer) ----
  k_prior_fused<<<dim3(256), B, 0, stream>>>(
      out + 405504, Wp1_i, Wp1_h, bp1_i, bp1_h, Wp2_i, Wp2_h, bp2_i, bp2_h,
      h1S, h2S, rT, flags + 384 * FSTRIDE);
  k_prior_out<<<dim3(768), B, 0, stream>>>(h2S, Wpm, bpm, Wplv, bplv,
                                           out, k3a, k3b);

  // ---- recon (bf16 MFMA) ----
  k_build_zf<<<dim3(1536), B, 0, stream>>>(out, zf);
  k_f32_to_bf16<<<dim3(1536), B, 0, stream>>>(zf, zf16, 3072 * 128);
  gemm_bf16_mfma<<<dim3(24, 157), B, 0, stream>>>(zf16, Wd16, bd,
                                                  out + 1191936, 3072, 20000, 128);
}

// Round 17
// 4536.746 us; speedup vs baseline: 2.2802x; 1.0222x over previous
//
#include <hip/hip_runtime.h>
#include <stdint.h>
#include <stddef.h>

#define DEV __device__ __forceinline__

typedef float f32x4 __attribute__((ext_vector_type(4)));
typedef short bf16x8 __attribute__((ext_vector_type(8)));

// ---------------- threefry2x32 (exact JAX) ----------------
__host__ __device__ inline void tf2x32(uint32_t k0, uint32_t k1,
                                       uint32_t x0, uint32_t x1,
                                       uint32_t* o0, uint32_t* o1) {
  uint32_t ks2 = k0 ^ k1 ^ 0x1BD11BDAu;
  uint32_t ks[3] = {k0, k1, ks2};
  x0 += k0; x1 += k1;
  const uint32_t R[8] = {13u,15u,26u,6u,17u,29u,16u,24u};
  for (int r = 0; r < 5; ++r) {
    const uint32_t* rot = (r & 1) ? (R + 4) : R;
    for (int i = 0; i < 4; ++i) {
      x0 += x1;
      uint32_t d = rot[i];
      x1 = (x1 << d) | (x1 >> (32u - d));
      x1 ^= x0;
    }
    x0 += ks[(r + 1) % 3];
    x1 += ks[(r + 2) % 3] + (uint32_t)(r + 1);
  }
  *o0 = x0; *o1 = x1;
}

DEV float erfinv_approx(float x) {
  float w = -logf((1.0f - x) * (1.0f + x));
  float p;
  if (w < 5.0f) {
    w = w - 2.5f;
    p = 2.81022636e-08f;
    p = fmaf(p, w, 3.43273939e-07f);
    p = fmaf(p, w, -3.5233877e-06f);
    p = fmaf(p, w, -4.39150654e-06f);
    p = fmaf(p, w, 0.00021858087f);
    p = fmaf(p, w, -0.00125372503f);
    p = fmaf(p, w, -0.00417768164f);
    p = fmaf(p, w, 0.246640727f);
    p = fmaf(p, w, 1.50140941f);
  } else {
    w = sqrtf(w) - 3.0f;
    p = -0.000200214257f;
    p = fmaf(p, w, 0.000100950558f);
    p = fmaf(p, w, 0.00134934322f);
    p = fmaf(p, w, -0.00367342844f);
    p = fmaf(p, w, 0.00573950773f);
    p = fmaf(p, w, -0.0076224613f);
    p = fmaf(p, w, 0.00943887047f);
    p = fmaf(p, w, 1.00167406f);
    p = fmaf(p, w, 2.83297682f);
  }
  return p * x;
}

DEV float normal_part(uint32_t ka, uint32_t kb, uint32_t idx) {
  uint32_t b1, b2;
  tf2x32(ka, kb, 0u, idx, &b1, &b2);
  uint32_t bits = b1 ^ b2;
  float f = __uint_as_float((bits >> 9) | 0x3f800000u) - 1.0f;
  const float lo = -0.99999994f;
  float u = f * 2.0f + lo;
  u = fmaxf(lo, u);
  return 1.41421356f * erfinv_approx(u);
}

DEV float lrelu(float x) { return x >= 0.f ? x : 0.2f * x; }
DEV float sigm(float x) { return 1.0f / (1.0f + expf(-x)); }

DEV float gru_out(float ir, float iz, float ig, float hr, float hz, float hg, float hprev) {
  float r = sigm(ir + hr);
  float z = sigm(iz + hz);
  float n = tanhf(ig + r * hg);
  return (1.0f - z) * n + z * hprev;
}

DEV float dot4f(float4 a, float4 b, float acc) {
  return fmaf(a.x, b.x, fmaf(a.y, b.y, fmaf(a.z, b.z, fmaf(a.w, b.w, acc))));
}

template <int K4>
DEV void dot2(const float* __restrict__ h, const float* __restrict__ w0,
              const float* __restrict__ w1, float& a0, float& a1) {
  const float4* h4 = (const float4*)h;
  const float4* p0 = (const float4*)w0;
  const float4* p1 = (const float4*)w1;
  #pragma unroll 4
  for (int k = 0; k < K4; ++k) {
    float4 hv = h4[k];
    float4 v0 = p0[k], v1 = p1[k];
    a0 = dot4f(hv, v0, a0);
    a1 = dot4f(hv, v1, a1);
  }
}

// simple global k-packed 3-gate dot (small K=64 rT dot)
template <int K4>
DEV void dotT3p(const float* __restrict__ hp, int b,
                const float* __restrict__ w0, const float* __restrict__ w1,
                const float* __restrict__ w2, float& a0, float& a1, float& a2) {
  const float4* __restrict__ w04 = (const float4*)w0;
  const float4* __restrict__ w14 = (const float4*)w1;
  const float4* __restrict__ w24 = (const float4*)w2;
  const float4* __restrict__ h4 = (const float4*)hp;
  #pragma unroll
  for (int k4 = 0; k4 < K4; ++k4) {
    float4 hv = h4[k4 * 64 + b];
    a0 = dot4f(w04[k4], hv, a0);
    a1 = dot4f(w14[k4], hv, a1);
    a2 = dot4f(w24[k4], hv, a2);
  }
}

// LDS k-packed 3-gate dot: h tile staged in LDS [k4][b][4].
template <int K4>
DEV void dotT3_lds(const float* __restrict__ hl, int b,
                   const float* __restrict__ w0, const float* __restrict__ w1,
                   const float* __restrict__ w2, float& a0, float& a1, float& a2) {
  const float4* __restrict__ h4 = (const float4*)hl;
  const float4* __restrict__ w04 = (const float4*)w0;
  const float4* __restrict__ w14 = (const float4*)w1;
  const float4* __restrict__ w24 = (const float4*)w2;
  #pragma unroll 8
  for (int k4 = 0; k4 < K4; ++k4) {
    float4 hv = h4[k4 * 64 + b];
    a0 = dot4f(w04[k4], hv, a0);
    a1 = dot4f(w14[k4], hv, a1);
    a2 = dot4f(w24[k4], hv, a2);
  }
}

// cooperative stage: N16 float4 per thread, global -> LDS, 16-deep batches.
template <int N16>
DEV void stage_lds(float* __restrict__ dst, const float* __restrict__ src) {
  const float4* __restrict__ s4 = (const float4*)src;
  float4* __restrict__ d4 = (float4*)dst;
  int tid = threadIdx.x;
  constexpr int CH = (N16 < 16) ? N16 : 16;
  #pragma unroll
  for (int r = 0; r < N16; r += CH) {
    float4 v[CH];
    #pragma unroll
    for (int u = 0; u < CH; ++u) v[u] = s4[(size_t)(r + u) * 256 + tid];
    #pragma unroll
    for (int u = 0; u < CH; ++u) d4[(size_t)(r + u) * 256 + tid] = v[u];
  }
}

// packed element offset for h[k][b] in k-packed layout
DEV size_t pk(int k, int b) { return (size_t)(k >> 2) * 256 + b * 4 + (k & 3); }

// ---------------- write-through (cross-XCD coherent) access, no cache flushes ----
DEV void coh_store_i(int* p, int v) {
  asm volatile("global_store_dword %0, %1, off sc0 sc1" :: "v"(p), "v"(v) : "memory");
}
DEV void coh_store_f(float* p, float v) {
  asm volatile("global_store_dword %0, %1, off sc0 sc1" :: "v"(p), "v"(v) : "memory");
}
DEV void coh_store_f4(float* p, f32x4 v) {
  asm volatile("global_store_dwordx4 %0, %1, off sc0 sc1" :: "v"(p), "v"(v) : "memory");
}
DEV int coh_load_i(const int* p) {
  int v;
  asm volatile("global_load_dword %0, %1, off sc0 sc1\n\ts_waitcnt vmcnt(0)"
               : "=v"(v) : "v"(p) : "memory");
  return v;
}

// ---------------- flag barrier with ONE CACHELINE PER BLOCK ----------------
#define FSTRIDE 32

DEV void flag_barrier(int* __restrict__ flags, int nblk, int myidx, int gen) {
  asm volatile("s_waitcnt vmcnt(0)" ::: "memory");
  __syncthreads();
  if (threadIdx.x == 0) coh_store_i(flags + (size_t)myidx * FSTRIDE, gen);
  if ((int)threadIdx.x < nblk) {
    int spins = 0;
    while (coh_load_i(flags + (size_t)threadIdx.x * FSTRIDE) < gen) {
      __builtin_amdgcn_s_sleep(4);
      if (++spins > (1 << 21)) break;  // failsafe
    }
  }
  __syncthreads();
}

DEV void wait_group(const int* __restrict__ flags, int nblk, int thr) {
  if ((int)threadIdx.x < nblk) {
    int spins = 0;
    while (coh_load_i(flags + (size_t)threadIdx.x * FSTRIDE) < thr) {
      __builtin_amdgcn_s_sleep(4);
      if (++spins > (1 << 21)) break;
    }
  }
  __syncthreads();
}

// stage 4 waves' scalars -> coalesced dwordx4 write-through
DEV void store_packed_tile4(float* dst_t, const float (*smem)[64], int j0) {
  if (threadIdx.x < 64) {
    int bb = threadIdx.x;
    f32x4 v;
    v.x = smem[0][bb];
    v.y = smem[1][bb];
    v.z = smem[2][bb];
    v.w = smem[3][bb];
    coh_store_f4(dst_t + (size_t)(j0 >> 2) * 256 + bb * 4, v);
  }
}

// ---------------- generic f32 GEMM ----------------
#define GBM 128
#define GBN 128
#define GBK 16

__global__ __launch_bounds__(256) void gemm_nt(
    const float* __restrict__ A, const float* __restrict__ Bt,
    const float* __restrict__ bias, float* __restrict__ C,
    int M, int N, int K, const int* __restrict__ gatherA, int trGI) {
  __shared__ float As[GBK][GBM + 4];
  __shared__ float Bs[GBK][GBN + 4];
  const int bm = blockIdx.y * GBM;
  const int bn = blockIdx.x * GBN;
  const int tid = threadIdx.x;
  const int tx = tid & 15;
  const int ty = tid >> 4;
  float acc[8][8];
  #pragma unroll
  for (int i = 0; i < 8; ++i)
    #pragma unroll
    for (int j = 0; j < 8; ++j) acc[i][j] = 0.f;

  for (int k0 = 0; k0 < K; k0 += GBK) {
    #pragma unroll
    for (int s = 0; s < 2; ++s) {
      int f = tid + s * 256;
      int r = f >> 2, kq = f & 3;
      int row = bm + r;
      float4 v = make_float4(0.f, 0.f, 0.f, 0.f);
      if (row < M) {
        int ar = gatherA ? gatherA[row] : row;
        v = *(const float4*)&A[(size_t)ar * K + k0 + kq * 4];
      }
      As[kq * 4 + 0][r] = v.x;
      As[kq * 4 + 1][r] = v.y;
      As[kq * 4 + 2][r] = v.z;
      As[kq * 4 + 3][r] = v.w;
    }
    #pragma unroll
    for (int s = 0; s < 2; ++s) {
      int f = tid + s * 256;
      int r = f >> 2, kq = f & 3;
      int col = bn + r;
      float4 v = make_float4(0.f, 0.f, 0.f, 0.f);
      if (col < N) v = *(const float4*)&Bt[(size_t)col * K + k0 + kq * 4];
      Bs[kq * 4 + 0][r] = v.x;
      Bs[kq * 4 + 1][r] = v.y;
      Bs[kq * 4 + 2][r] = v.z;
      Bs[kq * 4 + 3][r] = v.w;
    }
    __syncthreads();
    #pragma unroll
    for (int kk = 0; kk < GBK; ++kk) {
      float4 a0 = *(const float4*)&As[kk][ty * 4];
      float4 a1 = *(const float4*)&As[kk][64 + ty * 4];
      float4 b0 = *(const float4*)&Bs[kk][tx * 4];
      float4 b1 = *(const float4*)&Bs[kk][64 + tx * 4];
      float av[8] = {a0.x, a0.y, a0.z, a0.w, a1.x, a1.y, a1.z, a1.w};
      float bv[8] = {b0.x, b0.y, b0.z, b0.w, b1.x, b1.y, b1.z, b1.w};
      #pragma unroll
      for (int i = 0; i < 8; ++i)
        #pragma unroll
        for (int j = 0; j < 8; ++j)
          acc[i][j] = fmaf(av[i], bv[j], acc[i][j]);
    }
    __syncthreads();
  }
  #pragma unroll
  for (int i = 0; i < 8; ++i) {
    int row = bm + ((i < 4) ? (ty * 4 + i) : (64 + ty * 4 + i - 4));
    if (row >= M) continue;
    if (trGI) {
      #pragma unroll
      for (int j = 0; j < 8; ++j) {
        int col = bn + ((j < 4) ? (tx * 4 + j) : (64 + tx * 4 + j - 4));
        if (col >= N) continue;
        float v = acc[i][j] + (bias ? bias[col] : 0.f);
        int bb = row / 48, tt = row - bb * 48;
        C[((size_t)tt * N + col) * 64 + bb] = v;
      }
    } else {
      #pragma unroll
      for (int g = 0; g < 2; ++g) {
        int col0 = bn + g * 64 + tx * 4;
        if (col0 + 3 >= N) continue;
        float4 v;
        v.x = acc[i][g * 4 + 0] + (bias ? bias[col0 + 0] : 0.f);
        v.y = acc[i][g * 4 + 1] + (bias ? bias[col0 + 1] : 0.f);
        v.z = acc[i][g * 4 + 2] + (bias ? bias[col0 + 2] : 0.f);
        v.w = acc[i][g * 4 + 3] + (bias ? bias[col0 + 3] : 0.f);
        *(float4*)&C[(size_t)row * N + col0] = v;
      }
    }
  }
}

// ---------------- bf16 conversion + MFMA GEMM ----------------
__global__ void k_f32_to_bf16(const float* __restrict__ src,
                              unsigned short* __restrict__ dst, int n) {
  int i = blockIdx.x * 256 + threadIdx.x;
  if (i >= n) return;
  uint32_t u = __float_as_uint(src[i]);
  uint32_t r = (u + 0x7fffu + ((u >> 16) & 1u)) >> 16;
  dst[i] = (unsigned short)r;
}

// C = A16[M,K] @ B16[N,K]^T + bias. bf16 MFMA 16x16x32.
// trGI=0: C[M,N] normal. trGI=1: C scattered as giT[t][N][64] with row=b*48+t.
__global__ __launch_bounds__(256) void gemm_bf16_mfma(
    const unsigned short* __restrict__ A16, const unsigned short* __restrict__ B16,
    const float* __restrict__ bias, float* __restrict__ C,
    int M, int N, int K, int trGI) {
  int bm = blockIdx.x * 128;
  int bn = blockIdx.y * 128;
  int wave = threadIdx.x >> 6;
  int lane = threadIdx.x & 63;
  int wm = (wave & 1) * 64;
  int wn = (wave >> 1) * 64;
  int l15 = lane & 15;
  int kg = lane >> 4;
  f32x4 acc[4][4];
  #pragma unroll
  for (int mi = 0; mi < 4; ++mi)
    #pragma unroll
    for (int ni = 0; ni < 4; ++ni)
      acc[mi][ni] = (f32x4){0.f, 0.f, 0.f, 0.f};

  for (int kk = 0; kk < K; kk += 32) {
    bf16x8 afrag[4], bfrag[4];
    #pragma unroll
    for (int mi = 0; mi < 4; ++mi) {
      int row = bm + wm + mi * 16 + l15;
      afrag[mi] = *(const bf16x8*)&A16[(size_t)row * K + kk + kg * 8];
    }
    #pragma unroll
    for (int ni = 0; ni < 4; ++ni) {
      int col = bn + wn + ni * 16 + l15;
      if (col >= N) col = N - 1;  // clamp (stores guarded)
      bfrag[ni] = *(const bf16x8*)&B16[(size_t)col * K + kk + kg * 8];
    }
    #pragma unroll
    for (int mi = 0; mi < 4; ++mi)
      #pragma unroll
      for (int ni = 0; ni < 4; ++ni)
        acc[mi][ni] = __builtin_amdgcn_mfma_f32_16x16x32_bf16(
            afrag[mi], bfrag[ni], acc[mi][ni], 0, 0, 0);
  }
  // C/D: col = lane&15, row = (lane>>4)*4 + reg  [m89-verified]
  #pragma unroll
  for (int mi = 0; mi < 4; ++mi) {
    #pragma unroll
    for (int ni = 0; ni < 4; ++ni) {
      int col = bn + wn + ni * 16 + l15;
      if (col >= N) continue;
      int rowb = bm + wm + mi * 16 + kg * 4;
      float bv = bias ? bias[col] : 0.f;
      if (trGI) {
        #pragma unroll
        for (int r = 0; r < 4; ++r) {
          int row = rowb + r;
          int bb = row / 48, tt = row - bb * 48;
          C[((size_t)tt * N + col) * 64 + bb] = acc[mi][ni][r] + bv;
        }
      } else {
        #pragma unroll
        for (int r = 0; r < 4; ++r)
          C[(size_t)(rowb + r) * N + col] = acc[mi][ni][r] + bv;
      }
    }
  }
}

// ---------------- misc small kernels ----------------
__global__ void k_transpose(const float* __restrict__ W, float* __restrict__ Wt,
                            int rows, int cols) {
  int idx = blockIdx.x * 256 + threadIdx.x;
  if (idx >= rows * cols) return;
  int r = idx / cols, c = idx % cols;
  Wt[(size_t)c * rows + r] = W[idx];
}

__global__ void k_count_deg(const int* __restrict__ dst, int* __restrict__ deg, int nE) {
  int e = blockIdx.x * 256 + threadIdx.x;
  if (e < nE) atomicAdd(&deg[dst[e]], 1);
}

__global__ __launch_bounds__(1024) void k_scan(const int* __restrict__ deg,
                                               int* __restrict__ off,
                                               int* __restrict__ cursor, int n) {
  __shared__ int tmp[1024];
  __shared__ int carry_s;
  if (threadIdx.x == 0) carry_s = 0;
  __syncthreads();
  for (int base = 0; base < n; base += 1024) {
    int i = base + (int)threadIdx.x;
    int v = (i < n) ? deg[i] : 0;
    tmp[threadIdx.x] = v;
    __syncthreads();
    for (int s = 1; s < 1024; s <<= 1) {
      int t = (threadIdx.x >= (unsigned)s) ? tmp[threadIdx.x - s] : 0;
      __syncthreads();
      tmp[threadIdx.x] += t;
      __syncthreads();
    }
    int incl = tmp[threadIdx.x];
    int base_c = carry_s;
    int excl = incl - v;
    if (i < n) { off[i] = base_c + excl; cursor[i] = base_c + excl; }
    __syncthreads();
    if (threadIdx.x == 1023) carry_s = base_c + incl;
    __syncthreads();
  }
  if (threadIdx.x == 0) off[n] = carry_s;
}

__global__ void k_scatter(const int* __restrict__ dst, int* __restrict__ cursor,
                          int* __restrict__ csr, int nE) {
  int e = blockIdx.x * 256 + threadIdx.x;
  if (e < nE) {
    int pos = atomicAdd(&cursor[dst[e]], 1);
    csr[pos] = e;
  }
}

__global__ void k_alpha(const float* __restrict__ xW, const float* __restrict__ att_src,
                        const float* __restrict__ att_dst, float* __restrict__ as_,
                        float* __restrict__ ad_) {
  int i = blockIdx.x * 256 + threadIdx.x;
  if (i >= 80000) return;
  int n = i >> 2, h = i & 3;
  const float* xr = xW + (size_t)n * 256 + h * 64;
  const float* s = att_src + h * 64;
  const float* d = att_dst + h * 64;
  float a = 0.f, b = 0.f;
  dot2<16>(xr, s, d, a, b);
  as_[i] = a;
  ad_[i] = b;
}

__global__ __launch_bounds__(256) void k_gat_node(
    const float* __restrict__ xW, const float* __restrict__ as_,
    const float* __restrict__ ad_, const int* __restrict__ off,
    const int* __restrict__ csr, const int* __restrict__ esrc,
    const float* __restrict__ eattr, const float* __restrict__ gat_bias,
    float* __restrict__ p) {
  int n = blockIdx.x;
  int h = threadIdx.x >> 6;
  int c = threadIdx.x & 63;
  int s0 = off[n], s1 = off[n + 1];
  float adn = ad_[n * 4 + h];
  float m = -3.0e38f;
  for (int idx = s0; idx < s1; ++idx) {
    int e = csr[idx];
    int s = esrc[e];
    float ev = lrelu(as_[s * 4 + h] + adn);
    m = fmaxf(m, ev);
  }
  float sum = 0.f;
  for (int idx = s0; idx < s1; ++idx) {
    int e = csr[idx];
    int s = esrc[e];
    float ev = lrelu(as_[s * 4 + h] + adn);
    sum += expf(ev - m);
  }
  float acc = 0.f;
  for (int idx = s0; idx < s1; ++idx) {
    int e = csr[idx];
    int s = esrc[e];
    float ev = lrelu(as_[s * 4 + h] + adn);
    float w = expf(ev - m) / (sum + 1e-16f) * eattr[e];
    acc = fmaf(w, xW[(size_t)s * 256 + h * 64 + c], acc);
  }
  p[(size_t)n * 256 + h * 64 + c] = acc + gat_bias[h * 64 + c];
}

__global__ void k_build_X(const float* __restrict__ p, const float* __restrict__ tt,
                          const float* __restrict__ ct, const int* __restrict__ bx,
                          const int* __restrict__ btm, const int* __restrict__ bct,
                          float* __restrict__ X) {
  int idx = blockIdx.x * 256 + threadIdx.x;
  if (idx >= 3072 * 768) return;
  int rl = idx / 768, c = idx % 768;
  float v;
  if (c < 256) v = p[(size_t)bx[rl] * 256 + c];
  else if (c < 512) v = tt[(size_t)btm[rl] * 256 + (c - 256)];
  else v = ct[(size_t)bct[rl] * 256 + (c - 512)];
  X[idx] = v;
}

// ---------------- persistent fused GRU scans (R15 structure) ----------------
__global__ __launch_bounds__(256, 1) void k_gru_bidir_fused(
    const float* __restrict__ giT_f, const float* __restrict__ giT_b,
    const float* __restrict__ Wh_f, const float* __restrict__ bh_f,
    const float* __restrict__ Wh_b, const float* __restrict__ bh_b,
    float* __restrict__ features, float* __restrict__ hTb,
    int* __restrict__ flags) {
  __shared__ float lds_h[32768];
  __shared__ float smem[4][64];
  int w = threadIdx.x >> 6;
  int b = threadIdx.x & 63;
  int slot = blockIdx.x * 4 + w;
  int dir = slot >> 9;
  int j = slot & 511;
  int j0 = (blockIdx.x * 4) & 511;
  int gbid = blockIdx.x & 127;
  int* gflags = flags + (size_t)dir * 128 * FSTRIDE;
  const float* Wh = dir ? Wh_b : Wh_f;
  const float* bh = dir ? bh_b : bh_f;
  const float* gi = dir ? giT_b : giT_f;
  const float* w0 = Wh + (size_t)j * 512;
  const float* w1 = Wh + (size_t)(512 + j) * 512;
  const float* w2 = Wh + (size_t)(1024 + j) * 512;
  float bhr = bh[j], bhz = bh[512 + j], bhg = bh[1024 + j];
  float* hD = hTb + (size_t)dir * 48 * 32768;
  for (int s = 0; s < 48; ++s) {
    int t = dir ? (47 - s) : s;
    const float* gir = gi + (size_t)t * 98304;
    float giv0 = gir[j * 64 + b];
    float giv1 = gir[(512 + j) * 64 + b];
    float giv2 = gir[(1024 + j) * 64 + b];
    float hr = bhr, hz = bhz, hg = bhg, hprev = 0.f;
    if (s > 0) {
      int tp = dir ? (t + 1) : (t - 1);
      stage_lds<32>(lds_h, hD + (size_t)tp * 32768);
      __syncthreads();
      dotT3_lds<128>(lds_h, b, w0, w1, w2, hr, hz, hg);
      hprev = lds_h[pk(j, b)];
    }
    float hnew = gru_out(giv0, giv1, giv2, hr, hz, hg, hprev);
    smem[w][b] = hnew;
    features[((size_t)(b * 48 + t)) * 1024 + dir * 512 + j] = hnew;
    __syncthreads();
    store_packed_tile4(hD + (size_t)t * 32768, smem, j0);
    flag_barrier(gflags, 128, gbid, s + 1);
  }
}

__global__ __launch_bounds__(256, 1) void k_gru_u_fused(
    const float* __restrict__ giT, const float* __restrict__ Wh,
    const float* __restrict__ bh, float* __restrict__ r_feat,
    float* __restrict__ hU, int* __restrict__ flags) {
  __shared__ float lds_h[32768];
  __shared__ float smem[4][64];
  int w = threadIdx.x >> 6;
  int b = threadIdx.x & 63;
  int j = blockIdx.x * 4 + w;
  int j0 = blockIdx.x * 4;
  const float* w0 = Wh + (size_t)j * 512;
  const float* w1 = Wh + (size_t)(512 + j) * 512;
  const float* w2 = Wh + (size_t)(1024 + j) * 512;
  float bhr = bh[j], bhz = bh[512 + j], bhg = bh[1024 + j];
  for (int s = 0; s < 48; ++s) {
    const float* gir = giT + (size_t)s * 98304;
    float giv0 = gir[j * 64 + b];
    float giv1 = gir[(512 + j) * 64 + b];
    float giv2 = gir[(1024 + j) * 64 + b];
    float hr = bhr, hz = bhz, hg = bhg, hprev = 0.f;
    if (s > 0) {
      stage_lds<32>(lds_h, hU + (size_t)(s - 1) * 32768);
      __syncthreads();
      dotT3_lds<128>(lds_h, b, w0, w1, w2, hr, hz, hg);
      hprev = lds_h[pk(j, b)];
    }
    float hnew = gru_out(giv0, giv1, giv2, hr, hz, hg, hprev);
    smem[w][b] = hnew;
    r_feat[((size_t)(b * 48 + s)) * 512 + j] = hnew;
    __syncthreads();
    store_packed_tile4(hU + (size_t)s * 32768, smem, j0);
    flag_barrier(flags, 128, blockIdx.x, s + 1);
  }
}

__global__ __launch_bounds__(256, 1) void k_prior_fused(
    const float* __restrict__ r_post,
    const float* __restrict__ Wp1_i, const float* __restrict__ Wp1_h,
    const float* __restrict__ bp1_i, const float* __restrict__ bp1_h,
    const float* __restrict__ Wp2_i, const float* __restrict__ Wp2_h,
    const float* __restrict__ bp2_i, const float* __restrict__ bp2_h,
    float* __restrict__ h1S, float* __restrict__ h2S,
    float* __restrict__ rT, int* __restrict__ flags) {
  __shared__ float lds_h[32768];
  __shared__ float smem[4][64];
  int w = threadIdx.x >> 6;
  int b = threadIdx.x & 63;
  int cell = blockIdx.x >> 7;
  int gbid = blockIdx.x & 127;
  int slot = blockIdx.x * 4 + w;
  int j = slot & 511;
  int j0 = (blockIdx.x * 4) & 511;
  int* flagsA = flags;
  int* flagsB = flags + (size_t)128 * FSTRIDE;

  if (cell == 0) {
    int tid = gbid * 256 + threadIdx.x;
    for (int x = tid; x < 48 * 64 * 64; x += 32768) {
      int b0 = x & 63;
      int i0 = (x >> 6) & 63;
      int t0 = x >> 12;
      coh_store_f(rT + (size_t)t0 * 4096 + pk(i0, b0),
                  r_post[((size_t)(b0 * 48 + t0)) * 64 + i0]);
    }
    flag_barrier(flagsA, 128, gbid, 1);

    const float* wi0 = Wp1_i + (size_t)j * 64;
    const float* wi1 = Wp1_i + (size_t)(512 + j) * 64;
    const float* wi2 = Wp1_i + (size_t)(1024 + j) * 64;
    const float* wh0 = Wp1_h + (size_t)j * 512;
    const float* wh1 = Wp1_h + (size_t)(512 + j) * 512;
    const float* wh2 = Wp1_h + (size_t)(1024 + j) * 512;
    float bir = bp1_i[j], biz = bp1_i[512 + j], big = bp1_i[1024 + j];
    float bhr = bp1_h[j], bhz = bp1_h[512 + j], bhg = bp1_h[1024 + j];
    for (int k = 0; k < 48; ++k) {
      float ir = bir, iz = biz, ig = big;
      float hr = bhr, hz = bhz, hg = bhg, hprev = 0.f;
      if (k > 0) {
        stage_lds<32>(lds_h, h1S + (size_t)(k - 1) * 32768);
        dotT3p<16>(rT + (size_t)(k - 1) * 4096, b, wi0, wi1, wi2, ir, iz, ig);
        __syncthreads();
        dotT3_lds<128>(lds_h, b, wh0, wh1, wh2, hr, hz, hg);
        hprev = lds_h[pk(j, b)];
      }
      smem[w][b] = gru_out(ir, iz, ig, hr, hz, hg, hprev);
      __syncthreads();
      store_packed_tile4(h1S + (size_t)k * 32768, smem, j0);
      flag_barrier(flagsA, 128, gbid, k + 2);
    }
  } else {
    const float* wi0 = Wp2_i + (size_t)j * 512;
    const float* wi1 = Wp2_i + (size_t)(512 + j) * 512;
    const float* wi2 = Wp2_i + (size_t)(1024 + j) * 512;
    const float* wh0 = Wp2_h + (size_t)j * 512;
    const float* wh1 = Wp2_h + (size_t)(512 + j) * 512;
    const float* wh2 = Wp2_h + (size_t)(1024 + j) * 512;
    float bir = bp2_i[j], biz = bp2_i[512 + j], big = bp2_i[1024 + j];
    float bhr = bp2_h[j], bhz = bp2_h[512 + j], bhg = bp2_h[1024 + j];
    for (int t = 0; t < 48; ++t) {
      wait_group(flagsA, 128, t + 2);
      stage_lds<32>(lds_h, h1S + (size_t)t * 32768);
      __syncthreads();
      float ir = bir, iz = biz, ig = big;
      dotT3_lds<128>(lds_h, b, wi0, wi1, wi2, ir, iz, ig);
      float hr = bhr, hz = bhz, hg = bhg, hprev = 0.f;
      if (t > 0) {
        __syncthreads();
        stage_lds<32>(lds_h, h2S + (size_t)(t - 1) * 32768);
        __syncthreads();
        dotT3_lds<128>(lds_h, b, wh0, wh1, wh2, hr, hz, hg);
        hprev = lds_h[pk(j, b)];
      }
      smem[w][b] = gru_out(ir, iz, ig, hr, hz, hg, hprev);
      __syncthreads();
      store_packed_tile4(h2S + (size_t)t * 32768, smem, j0);
      flag_barrier(flagsB, 128, gbid, t + 1);
    }
  }
}

// ---------------- heads / outputs ----------------
__global__ void k_s_head(const float* __restrict__ features,
                         const float* __restrict__ Ws_m, const float* __restrict__ bs_m,
                         const float* __restrict__ Ws_lv, const float* __restrict__ bs_lv,
                         float* __restrict__ out, uint32_t ka, uint32_t kb) {
  int idx = blockIdx.x * 256 + threadIdx.x;
  if (idx >= 4096) return;
  int i = idx & 63, b = idx >> 6;
  const float* fr = features + ((size_t)(b * 48 + 47)) * 1024;
  const float* bk = features + ((size_t)(b * 48 + 0)) * 1024 + 512;
  const float* wm = Ws_m + (size_t)i * 1024;
  const float* wl = Ws_lv + (size_t)i * 1024;
  float m = 0.f, lv = 0.f;
  dot2<128>(fr, wm, wl, m, lv);
  dot2<128>(bk, wm + 512, wl + 512, m, lv);
  m = lrelu(m + bs_m[i]);
  lv = lrelu(lv + bs_lv[i]);
  float nz = normal_part(ka, kb, (uint32_t)idx);
  out[idx] = m;
  out[4096 + idx] = lv;
  out[8192 + idx] = m + nz * expf(0.5f * lv);
}

__global__ void k_r_head(const float* __restrict__ r_feat,
                         const float* __restrict__ Wr_m, const float* __restrict__ br_m,
                         const float* __restrict__ Wr_lv, const float* __restrict__ br_lv,
                         float* __restrict__ out, uint32_t ka, uint32_t kb) {
  int idx = blockIdx.x * 256 + threadIdx.x;
  if (idx >= 196608) return;
  int i = idx & 63;
  int bt = idx >> 6;
  const float* f = r_feat + (size_t)bt * 512;
  float m = 0.f, lv = 0.f;
  dot2<128>(f, Wr_m + (size_t)i * 512, Wr_lv + (size_t)i * 512, m, lv);
  m += br_m[i];
  lv += br_lv[i];
  float nz = normal_part(ka, kb, (uint32_t)idx);
  out[12288 + idx] = m;
  out[208896 + idx] = lv;
  out[405504 + idx] = m + nz * expf(0.5f * lv);
}

__global__ void k_prior_out(const float* __restrict__ h2S,
                            const float* __restrict__ Wpm, const float* __restrict__ bpm,
                            const float* __restrict__ Wplv, const float* __restrict__ bplv,
                            float* __restrict__ out, uint32_t ka, uint32_t kb) {
  int idx = blockIdx.x * 256 + threadIdx.x;
  if (idx >= 196608) return;
  int i = idx & 63;
  int bt = idx >> 6;
  int b = bt & 63;
  int t = bt >> 6;
  const float4* h4 = (const float4*)(h2S + (size_t)t * 32768);
  const float4* wm4 = (const float4*)(Wpm + (size_t)i * 512);
  const float4* wl4 = (const float4*)(Wplv + (size_t)i * 512);
  float m = 0.f, lv = 0.f;
  #pragma unroll 8
  for (int k4 = 0; k4 < 128; ++k4) {
    float4 hv = h4[k4 * 64 + b];
    m = dot4f(wm4[k4], hv, m);
    lv = dot4f(wl4[k4], hv, lv);
  }
  m += bpm[i];
  lv += bplv[i];
  float ep = normal_part(ka, kb, (uint32_t)idx);
  float rp = m + ep * expf(0.5f * lv);
  size_t o = ((size_t)b * 48 + t) * 64 + i;
  out[602112 + o] = m;
  out[798720 + o] = lv;
  out[995328 + o] = rp;
}

__global__ void k_build_zf(const float* __restrict__ out, float* __restrict__ zf) {
  int idx = blockIdx.x * 256 + threadIdx.x;
  if (idx >= 3072 * 128) return;
  int row = idx >> 7, c = idx & 127;
  float v;
  if (c < 64) v = out[405504 + row * 64 + c];
  else v = out[8192 + (row / 48) * 64 + (c - 64)];
  zf[idx] = v;
}

// ---------------- launcher ----------------
extern "C" void kernel_launch(void* const* d_in, const int* in_sizes, int n_in,
                              void* d_out, int out_size, void* d_ws, size_t ws_size,
                              hipStream_t stream) {
  const int* graph_x = (const int*)d_in[0];
  const int* edge_index = (const int*)d_in[1];
  const float* edge_attr = (const float*)d_in[2];
  const int* batch_x = (const int*)d_in[3];
  const int* batch_time = (const int*)d_in[4];
  const int* batch_cat = (const int*)d_in[5];
  const float* node_emb = (const float*)d_in[8];
  const float* W_gat = (const float*)d_in[9];
  const float* att_src = (const float*)d_in[10];
  const float* att_dst = (const float*)d_in[11];
  const float* gat_bias = (const float*)d_in[12];
  const float* time_table = (const float*)d_in[13];
  const float* cat_table = (const float*)d_in[14];
  const float* W_w = (const float*)d_in[15];
  const float* b_w = (const float*)d_in[16];
  const float* Wi_f = (const float*)d_in[17];
  const float* Wh_f = (const float*)d_in[18];
  const float* bi_f = (const float*)d_in[19];
  const float* bh_f = (const float*)d_in[20];
  const float* Wi_bw = (const float*)d_in[21];
  const float* Wh_bw = (const float*)d_in[22];
  const float* bi_bw = (const float*)d_in[23];
  const float* bh_bw = (const float*)d_in[24];
  const float* Wi_u = (const float*)d_in[25];
  const float* Wh_u = (const float*)d_in[26];
  const float* bi_u = (const float*)d_in[27];
  const float* bh_u = (const float*)d_in[28];
  const float* Ws_m = (const float*)d_in[29];
  const float* bs_m = (const float*)d_in[30];
  const float* Ws_lv = (const float*)d_in[31];
  const float* bs_lv = (const float*)d_in[32];
  const float* Wr_m = (const float*)d_in[33];
  const float* br_m = (const float*)d_in[34];
  const float* Wr_lv = (const float*)d_in[35];
  const float* br_lv = (const float*)d_in[36];
  const float* Wp1_i = (const float*)d_in[37];
  const float* Wp1_h = (const float*)d_in[38];
  const float* bp1_i = (const float*)d_in[39];
  const float* bp1_h = (const float*)d_in[40];
  const float* Wp2_i = (const float*)d_in[41];
  const float* Wp2_h = (const float*)d_in[42];
  const float* bp2_i = (const float*)d_in[43];
  const float* bp2_h = (const float*)d_in[44];
  const float* Wpm = (const float*)d_in[45];
  const float* bpm = (const float*)d_in[46];
  const float* Wplv = (const float*)d_in[47];
  const float* bplv = (const float*)d_in[48];
  const float* Wd = (const float*)d_in[49];
  const float* bd = (const float*)d_in[50];
  float* out = (float*)d_out;

  uint32_t k1a, k1b, k2a, k2b, k3a, k3b;
  tf2x32(0u, 42u, 0u, 0u, &k1a, &k1b);
  tf2x32(0u, 42u, 0u, 1u, &k2a, &k2b);
  tf2x32(0u, 42u, 0u, 2u, &k3a, &k3b);

  float* ws = (float*)d_ws;
  size_t o = 0;
  auto alloc = [&](size_t n) { float* q = ws + o; o += n; return q; };
  float* R1 = alloc(5120000);
  float* R2 = alloc(5120000);
  float* R3 = alloc(4718592);
  float* R4 = alloc(786432);
  float* as_ = alloc(80000);
  float* ad_ = alloc(80000);
  float* Wgt = alloc(65536);
  int* deg = (int*)alloc(20000);
  int* off = (int*)alloc(20001);
  int* cursor = (int*)alloc(20000);
  int* csr = (int*)alloc(320000);
  float* rT = alloc(196608);
  int* flags = (int*)alloc(32768);  // 640 padded flags x 32 ints

  float* xW = R1;
  float* features = R1;
  float* r_feat = R1 + 3145728;
  float* p = R2;
  float* giT_b = R2;
  float* hU = R2;
  float* X = R3;
  float* giT_f = R3;
  float* giT_u = R3;
  float* h1S = R3;
  float* h2S = R3 + 1572864;
  float* ph = R4;
  float* zf = R4;
  // bf16 staging (lifetimes verified stream-ordered):
  unsigned short* ph16 = (unsigned short*)R1;                 // pre-bidir (xW dead)
  unsigned short* Wif16 = (unsigned short*)(R1 + 1000000);
  unsigned short* Wib16 = (unsigned short*)(R1 + 1500000);
  unsigned short* Wiu16 = (unsigned short*)R2;                // post-bidir (giT_b dead)
  unsigned short* feat16 = (unsigned short*)(R2 + 1000000);
  unsigned short* Wd16 = (unsigned short*)R2;                 // post-u (hU dead)
  unsigned short* zf16 = (unsigned short*)(R4 + 458752);
  float* hTb = out + 1191936;

  const int* esrc = edge_index;
  const int* edst = edge_index + 320000;

  dim3 B(256);

  (void)hipMemsetAsync(deg, 0, 20000 * sizeof(int), stream);
  (void)hipMemsetAsync(flags, 0, 32768 * sizeof(int), stream);

  // ---- GAT ----
  k_transpose<<<dim3(256), B, 0, stream>>>(W_gat, Wgt, 256, 256);
  k_count_deg<<<dim3(1250), B, 0, stream>>>(edst, deg, 320000);
  k_scan<<<dim3(1), dim3(1024), 0, stream>>>(deg, off, cursor, 20000);
  k_scatter<<<dim3(1250), B, 0, stream>>>(edst, cursor, csr, 320000);
  gemm_nt<<<dim3(2, 157), B, 0, stream>>>(node_emb, Wgt, nullptr, xW,
                                          20000, 256, 256, graph_x, 0);
  k_alpha<<<dim3(313), B, 0, stream>>>(xW, att_src, att_dst, as_, ad_);
  k_gat_node<<<dim3(20000), B, 0, stream>>>(xW, as_, ad_, off, csr, esrc,
                                            edge_attr, gat_bias, p);

  // ---- embed concat + W_w ----
  k_build_X<<<dim3(9216), B, 0, stream>>>(p, time_table, cat_table, batch_x,
                                          batch_time, batch_cat, X);
  gemm_nt<<<dim3(2, 24), B, 0, stream>>>(X, W_w, b_w, ph, 3072, 256, 768,
                                         nullptr, 0);

  // ---- gi precompute (bf16 MFMA) + fused bidirectional GRU ----
  k_f32_to_bf16<<<dim3(3072), B, 0, stream>>>(ph, ph16, 3072 * 256);
  k_f32_to_bf16<<<dim3(1536), B, 0, stream>>>(Wi_f, Wif16, 1536 * 256);
  k_f32_to_bf16<<<dim3(1536), B, 0, stream>>>(Wi_bw, Wib16, 1536 * 256);
  gemm_bf16_mfma<<<dim3(24, 12), B, 0, stream>>>(ph16, Wif16, bi_f, giT_f,
                                                 3072, 1536, 256, 1);
  gemm_bf16_mfma<<<dim3(24, 12), B, 0, stream>>>(ph16, Wib16, bi_bw, giT_b,
                                                 3072, 1536, 256, 1);
  k_gru_bidir_fused<<<dim3(256), B, 0, stream>>>(
      giT_f, giT_b, Wh_f, bh_f, Wh_bw, bh_bw, features, hTb, flags);

  // ---- s head ----
  k_s_head<<<dim3(16), B, 0, stream>>>(features, Ws_m, bs_m, Ws_lv, bs_lv,
                                       out, k1a, k1b);

  // ---- r_feat GRU (gi via bf16 MFMA) ----
  k_f32_to_bf16<<<dim3(12288), B, 0, stream>>>(features, feat16, 3072 * 1024);
  k_f32_to_bf16<<<dim3(6144), B, 0, stream>>>(Wi_u, Wiu16, 1536 * 1024);
  gemm_bf16_mfma<<<dim3(24, 12), B, 0, stream>>>(feat16, Wiu16, bi_u, giT_u,
                                                 3072, 1536, 1024, 1);
  k_gru_u_fused<<<dim3(128), B, 0, stream>>>(giT_u, Wh_u, bh_u, r_feat,
                                             hU, flags + 256 * FSTRIDE);

  // ---- Wd -> bf16 (hU region now dead) ----
  k_f32_to_bf16<<<dim3(10000), B, 0, stream>>>(Wd, Wd16, 20000 * 128);

  // ---- r head ----
  k_r_head<<<dim3(768), B, 0, stream>>>(r_feat, Wr_m, br_m, Wr_lv, br_lv,
                                        out, k2a, k2b);

  // ---- prior scan (producer/consumer) ----
  k_prior_fused<<<dim3(256), B, 0, stream>>>(
      out + 405504, Wp1_i, Wp1_h, bp1_i, bp1_h, Wp2_i, Wp2_h, bp2_i, bp2_h,
      h1S, h2S, rT, flags + 384 * FSTRIDE);
  k_prior_out<<<dim3(768), B, 0, stream>>>(h2S, Wpm, bpm, Wplv, bplv,
                                           out, k3a, k3b);

  // ---- recon (bf16 MFMA) ----
  k_build_zf<<<dim3(1536), B, 0, stream>>>(out, zf);
  k_f32_to_bf16<<<dim3(1536), B, 0, stream>>>(zf, zf16, 3072 * 128);
  gemm_bf16_mfma<<<dim3(24, 157), B, 0, stream>>>(zf16, Wd16, bd,
                                                  out + 1191936, 3072, 20000, 128, 0);
}